// Round 2
// baseline (551.456 us; speedup 1.0000x reference)
//
#include <hip/hip_runtime.h>

#define N_NODES 40000
#define N_EDGES 640000
#define IN_DIM 128
#define HID_DIM 256
#define OUT_DIM 256
#define N_CLASSES 10
#define N_GRAPHS 128
#define NEG_SLOPE 0.01f

// ---------------- edge histogram (both directions) ----------------
__global__ __launch_bounds__(256) void hist_kernel(const int* __restrict__ src,
                                                   const int* __restrict__ dst,
                                                   int* __restrict__ cntOut,
                                                   int* __restrict__ cntIn, int nEdges) {
  int i = blockIdx.x * 256 + threadIdx.x;
  if (i < nEdges) {
    atomicAdd(&cntOut[src[i]], 1);
    atomicAdd(&cntIn[dst[i]], 1);
  }
}

// ---------------- single-block exclusive scan over cntIn -> rowptr, cursor ----------------
__global__ __launch_bounds__(256) void scan_kernel(const int* __restrict__ cnt,
                                                   int* __restrict__ rowptr,
                                                   int* __restrict__ cursor) {
  __shared__ int part[256];
  const int tid = threadIdx.x;
  constexpr int CHUNK = (N_NODES + 255) / 256;  // 157
  int begin = tid * CHUNK;
  int end = begin + CHUNK;
  if (end > N_NODES) end = N_NODES;
  int s = 0;
  for (int i = begin; i < end; i++) s += cnt[i];
  part[tid] = s;
  __syncthreads();
  // Hillis-Steele inclusive scan
  for (int off = 1; off < 256; off <<= 1) {
    int v = (tid >= off) ? part[tid - off] : 0;
    __syncthreads();
    part[tid] += v;
    __syncthreads();
  }
  int pre = (tid == 0) ? 0 : part[tid - 1];
  for (int i = begin; i < end; i++) {
    rowptr[i] = pre;
    cursor[i] = pre;
    pre += cnt[i];
  }
  if (tid == 255) rowptr[N_NODES] = part[255];  // total edges
}

// ---------------- fill CSR adjacency: eidx[bucket positions] = src ----------------
__global__ __launch_bounds__(256) void fill_kernel(const int* __restrict__ src,
                                                   const int* __restrict__ dst,
                                                   int* __restrict__ cursor,
                                                   int* __restrict__ eidx, int nEdges) {
  int e = blockIdx.x * 256 + threadIdx.x;
  if (e < nEdges) {
    int pos = atomicAdd(&cursor[dst[e]], 1);
    eidx[pos] = src[e];
  }
}

// ---------------- degree counts -> inverse sqrt scales ----------------
__global__ __launch_bounds__(256) void rsqrt2_kernel(const int* __restrict__ cntIn,
                                                     const int* __restrict__ cntOut,
                                                     float* __restrict__ sIn,
                                                     float* __restrict__ sOut, int n) {
  int i = blockIdx.x * 256 + threadIdx.x;
  if (i < n) {
    sIn[i] = rsqrtf((float)max(cntIn[i], 1));
    sOut[i] = rsqrtf((float)max(cntOut[i], 1));
  }
}

// ---------------- CSR gather: agg[v] = s_in[v] * sum_{u in N_in(v)} h[u]*s_out[u] ----------------
template <int D>
__global__ __launch_bounds__(256) void gather_kernel(const float* __restrict__ h,
                                                     const float* __restrict__ s_out,
                                                     const float* __restrict__ s_in,
                                                     const int* __restrict__ rowptr,
                                                     const int* __restrict__ eidx,
                                                     float* __restrict__ agg) {
  int node, f;
  if (D == 256) {
    node = blockIdx.x;           // uniform -> scalar loads for rowptr/eidx/s_out
    f = threadIdx.x;
  } else {
    node = blockIdx.x * 2 + (threadIdx.x >> 7);
    f = threadIdx.x & 127;
  }
  int beg = rowptr[node];
  int end = rowptr[node + 1];
  float acc = 0.0f;
  int j = beg;
  for (; j + 3 < end; j += 4) {
    int s0 = eidx[j + 0], s1 = eidx[j + 1], s2 = eidx[j + 2], s3 = eidx[j + 3];
    float a0 = h[(size_t)s0 * D + f];
    float a1 = h[(size_t)s1 * D + f];
    float a2 = h[(size_t)s2 * D + f];
    float a3 = h[(size_t)s3 * D + f];
    acc += a0 * s_out[s0];
    acc += a1 * s_out[s1];
    acc += a2 * s_out[s2];
    acc += a3 * s_out[s3];
  }
  for (; j < end; j++) {
    int s = eidx[j];
    acc += h[(size_t)s * D + f] * s_out[s];
  }
  agg[(size_t)node * D + f] = acc * s_in[node];
}

// ---------------- fused GEMM: O = lrelu(A @ W + b) ----------------
// A: [M,K] row-major (already fully normalized), W: [K,256] row-major, O: [M,256]
template <int K>
__global__ __launch_bounds__(256) void gemm_bias_lrelu(const float* __restrict__ A,
                                                       const float* __restrict__ W,
                                                       const float* __restrict__ bias,
                                                       float* __restrict__ O, int M) {
  constexpr int BM = 64, BN = 64, BK = 32;
  __shared__ float As[BK][BM + 4];
  __shared__ float Bs[BK][BN + 4];
  const int tid = threadIdx.x;
  const int tr = tid / 16;  // 0..15
  const int tc = tid % 16;  // 0..15
  const int rowBase = blockIdx.x * BM;
  const int colBase = blockIdx.y * BN;
  float acc[4][4] = {};

  for (int k0 = 0; k0 < K; k0 += BK) {
    // load A tile 64x32 (8 floats/thread), store transposed
#pragma unroll
    for (int p = 0; p < 2; p++) {
      int r = p * 32 + tid / 8;
      int c4 = tid % 8;
      float4 v = *reinterpret_cast<const float4*>(&A[(size_t)(rowBase + r) * K + k0 + c4 * 4]);
      As[c4 * 4 + 0][r] = v.x;
      As[c4 * 4 + 1][r] = v.y;
      As[c4 * 4 + 2][r] = v.z;
      As[c4 * 4 + 3][r] = v.w;
    }
    // load B tile 32x64
#pragma unroll
    for (int p = 0; p < 2; p++) {
      int k = p * 16 + tid / 16;
      int c4 = tid % 16;
      float4 v = *reinterpret_cast<const float4*>(&W[(size_t)(k0 + k) * 256 + colBase + c4 * 4]);
      *reinterpret_cast<float4*>(&Bs[k][c4 * 4]) = v;
    }
    __syncthreads();
#pragma unroll
    for (int k = 0; k < BK; k++) {
      float a[4], b[4];
#pragma unroll
      for (int i = 0; i < 4; i++) a[i] = As[k][tr * 4 + i];
#pragma unroll
      for (int j = 0; j < 4; j++) b[j] = Bs[k][tc * 4 + j];
#pragma unroll
      for (int i = 0; i < 4; i++)
#pragma unroll
        for (int j = 0; j < 4; j++) acc[i][j] += a[i] * b[j];
    }
    __syncthreads();
  }

  // epilogue: bias + leaky relu, float4 stores
#pragma unroll
  for (int i = 0; i < 4; i++) {
    int row = rowBase + tr * 4 + i;
    float4 o;
    float* po = &o.x;
#pragma unroll
    for (int j = 0; j < 4; j++) {
      float v = acc[i][j] + bias[colBase + tc * 4 + j];
      po[j] = v > 0.0f ? v : NEG_SLOPE * v;
    }
    *reinterpret_cast<float4*>(&O[(size_t)row * 256 + colBase + tc * 4]) = o;
  }
}

// ---------------- per-graph mean pooling (graph_ids sorted) ----------------
__global__ __launch_bounds__(256) void pool_kernel(const float* __restrict__ h,
                                                   const int* __restrict__ gids,
                                                   float* __restrict__ sums,
                                                   float* __restrict__ counts, int nNodes) {
  constexpr int NB = 32;  // nodes per block
  const int f = threadIdx.x;
  const int n0 = blockIdx.x * NB;
  float acc = 0.0f;
  int cur = -1;
  int cnt = 0;
  for (int i = 0; i < NB; i++) {
    int n = n0 + i;
    if (n >= nNodes) break;
    int g = gids[n];
    if (g != cur) {
      if (cur >= 0) {
        atomicAdd(&sums[(size_t)cur * 256 + f], acc);
        if (f == 0) atomicAdd(&counts[cur], (float)cnt);
      }
      cur = g;
      acc = 0.0f;
      cnt = 0;
    }
    acc += h[(size_t)n * 256 + f];
    cnt++;
  }
  if (cur >= 0) {
    atomicAdd(&sums[(size_t)cur * 256 + f], acc);
    if (f == 0) atomicAdd(&counts[cur], (float)cnt);
  }
}

// ---------------- classifier: out = (sums/count) @ Wc + bc ----------------
__global__ __launch_bounds__(256) void cls_kernel(const float* __restrict__ sums,
                                                  const float* __restrict__ counts,
                                                  const float* __restrict__ Wc,
                                                  const float* __restrict__ bc,
                                                  float* __restrict__ out) {
  __shared__ float hg[256];
  int g = blockIdx.x;
  float invc = 1.0f / fmaxf(counts[g], 1.0f);
  hg[threadIdx.x] = sums[(size_t)g * 256 + threadIdx.x] * invc;
  __syncthreads();
  if (threadIdx.x < N_CLASSES) {
    float a = bc[threadIdx.x];
    for (int k = 0; k < 256; k++) a += hg[k] * Wc[k * N_CLASSES + threadIdx.x];
    out[g * N_CLASSES + threadIdx.x] = a;
  }
}

static constexpr size_t align1k(size_t x) { return (x + 1023) & ~(size_t)1023; }

extern "C" void kernel_launch(void* const* d_in, const int* in_sizes, int n_in,
                              void* d_out, int out_size, void* d_ws, size_t ws_size,
                              hipStream_t stream) {
  const float* x = (const float*)d_in[0];
  const int* src = (const int*)d_in[1];
  const int* dst = (const int*)d_in[2];
  const int* gids = (const int*)d_in[3];
  const float* W1 = (const float*)d_in[4];
  const float* b1 = (const float*)d_in[5];
  const float* W2 = (const float*)d_in[6];
  const float* b2 = (const float*)d_in[7];
  const float* Wc = (const float*)d_in[8];
  const float* bc = (const float*)d_in[9];
  float* out = (float*)d_out;

  // ---------------- workspace layout ----------------
  char* ws = (char*)d_ws;
  constexpr size_t OFF_CNT_IN = 0;                                        // 40000 ints
  constexpr size_t OFF_CNT_OUT = OFF_CNT_IN + (size_t)N_NODES * 4;        // 40000 ints
  constexpr size_t OFF_ROWPTR = align1k(OFF_CNT_OUT + (size_t)N_NODES * 4);   // 40001 ints
  constexpr size_t OFF_CURSOR = align1k(OFF_ROWPTR + (size_t)(N_NODES + 1) * 4);
  constexpr size_t OFF_SIN = align1k(OFF_CURSOR + (size_t)N_NODES * 4);
  constexpr size_t OFF_SOUT = OFF_SIN + (size_t)N_NODES * 4;
  constexpr size_t OFF_PCNT = align1k(OFF_SOUT + (size_t)N_NODES * 4);    // 128 floats
  constexpr size_t OFF_SUMS = align1k(OFF_PCNT + 512);                    // 128*256 floats
  constexpr size_t OFF_EIDX = align1k(OFF_SUMS + (size_t)N_GRAPHS * 256 * 4);
  constexpr size_t OFF_AGG = align1k(OFF_EIDX + (size_t)N_EDGES * 4);
  constexpr size_t SZ_BIG = (size_t)N_NODES * 256 * 4;  // 40,960,000
  constexpr size_t OFF_H = align1k(OFF_AGG + SZ_BIG);

  int* cntIn = (int*)(ws + OFF_CNT_IN);
  int* cntOut = (int*)(ws + OFF_CNT_OUT);
  int* rowptr = (int*)(ws + OFF_ROWPTR);
  int* cursor = (int*)(ws + OFF_CURSOR);
  float* s_in = (float*)(ws + OFF_SIN);
  float* s_out = (float*)(ws + OFF_SOUT);
  float* counts = (float*)(ws + OFF_PCNT);
  float* sums = (float*)(ws + OFF_SUMS);
  int* eidx = (int*)(ws + OFF_EIDX);
  float* agg = (float*)(ws + OFF_AGG);
  float* h = (float*)(ws + OFF_H);

  // zero: histogram counters; pool counts+sums
  hipMemsetAsync(ws + OFF_CNT_IN, 0, 2 * (size_t)N_NODES * 4, stream);
  hipMemsetAsync(ws + OFF_PCNT, 0, OFF_SUMS + (size_t)N_GRAPHS * 256 * 4 - OFF_PCNT, stream);

  // ---------------- CSR build + degree scales ----------------
  hist_kernel<<<(N_EDGES + 255) / 256, 256, 0, stream>>>(src, dst, cntOut, cntIn, N_EDGES);
  scan_kernel<<<1, 256, 0, stream>>>(cntIn, rowptr, cursor);
  fill_kernel<<<(N_EDGES + 255) / 256, 256, 0, stream>>>(src, dst, cursor, eidx, N_EDGES);
  rsqrt2_kernel<<<(N_NODES + 255) / 256, 256, 0, stream>>>(cntIn, cntOut, s_in, s_out, N_NODES);

  // ---------------- layer 1 ----------------
  gather_kernel<IN_DIM><<<N_NODES / 2, 256, 0, stream>>>(x, s_out, s_in, rowptr, eidx, agg);
  {
    dim3 grid(N_NODES / 64, 256 / 64);
    gemm_bias_lrelu<IN_DIM><<<grid, 256, 0, stream>>>(agg, W1, b1, h, N_NODES);
  }

  // ---------------- layer 2 ----------------
  gather_kernel<HID_DIM><<<N_NODES, 256, 0, stream>>>(h, s_out, s_in, rowptr, eidx, agg);
  {
    dim3 grid(N_NODES / 64, 256 / 64);
    gemm_bias_lrelu<HID_DIM><<<grid, 256, 0, stream>>>(agg, W2, b2, h, N_NODES);
  }

  // ---------------- pooling + classifier ----------------
  pool_kernel<<<(N_NODES + 31) / 32, 256, 0, stream>>>(h, gids, sums, counts, N_NODES);
  cls_kernel<<<N_GRAPHS, 256, 0, stream>>>(sums, counts, Wc, bc, out);
}

// Round 5
// 453.422 us; speedup vs baseline: 1.2162x; 1.2162x over previous
//
#include <hip/hip_runtime.h>

#define N_NODES 40000
#define N_EDGES 640000
#define IN_DIM 128
#define HID_DIM 256
#define OUT_DIM 256
#define N_CLASSES 10
#define N_GRAPHS 128
#define NEG_SLOPE 0.01f

#define SCAN_BLOCKS ((N_NODES + 255) / 256)  // 157

// ---------------- edge histogram (both directions) ----------------
__global__ __launch_bounds__(256) void hist_kernel(const int* __restrict__ src,
                                                   const int* __restrict__ dst,
                                                   int* __restrict__ cntOut,
                                                   int* __restrict__ cntIn, int nEdges) {
  int i = blockIdx.x * 256 + threadIdx.x;
  if (i < nEdges) {
    atomicAdd(&cntOut[src[i]], 1);
    atomicAdd(&cntIn[dst[i]], 1);
  }
}

// ---------------- stage 1: per-block exclusive scan + block sums ----------------
__global__ __launch_bounds__(256) void scan1_kernel(const int* __restrict__ cnt,
                                                    int* __restrict__ rowptr,
                                                    int* __restrict__ blockSums) {
  __shared__ int sm[256];
  int i = blockIdx.x * 256 + threadIdx.x;
  int v = (i < N_NODES) ? cnt[i] : 0;
  sm[threadIdx.x] = v;
  __syncthreads();
  for (int off = 1; off < 256; off <<= 1) {
    int t = (threadIdx.x >= off) ? sm[threadIdx.x - off] : 0;
    __syncthreads();
    sm[threadIdx.x] += t;
    __syncthreads();
  }
  if (i < N_NODES) rowptr[i] = sm[threadIdx.x] - v;  // exclusive within block
  if (threadIdx.x == 255) blockSums[blockIdx.x] = sm[255];
}

// ---------------- stage 2: scan block sums (157 values) ----------------
__global__ __launch_bounds__(256) void scan2_kernel(const int* __restrict__ blockSums,
                                                    int* __restrict__ blockOff,
                                                    int* __restrict__ rowptr) {
  __shared__ int sm[256];
  int tid = threadIdx.x;
  int v = (tid < SCAN_BLOCKS) ? blockSums[tid] : 0;
  sm[tid] = v;
  __syncthreads();
  for (int off = 1; off < 256; off <<= 1) {
    int t = (tid >= off) ? sm[tid - off] : 0;
    __syncthreads();
    sm[tid] += t;
    __syncthreads();
  }
  if (tid < SCAN_BLOCKS) blockOff[tid] = sm[tid] - v;  // exclusive
  if (tid == 255) rowptr[N_NODES] = sm[255];           // total edges
}

// ---------------- stage 3: add offsets; init cursor; degree scales ----------------
__global__ __launch_bounds__(256) void scan3_kernel(int* __restrict__ rowptr,
                                                    const int* __restrict__ blockOff,
                                                    int* __restrict__ cursor,
                                                    const int* __restrict__ cntIn,
                                                    const int* __restrict__ cntOut,
                                                    float* __restrict__ sIn,
                                                    float* __restrict__ sOut) {
  int i = blockIdx.x * 256 + threadIdx.x;
  if (i < N_NODES) {
    int r = rowptr[i] + blockOff[blockIdx.x];
    rowptr[i] = r;
    cursor[i] = r;
    sIn[i] = rsqrtf((float)max(cntIn[i], 1));
    sOut[i] = rsqrtf((float)max(cntOut[i], 1));
  }
}

// ---------------- fill CSR adjacency: eidx[bucket positions] = src ----------------
__global__ __launch_bounds__(256) void fill_kernel(const int* __restrict__ src,
                                                   const int* __restrict__ dst,
                                                   int* __restrict__ cursor,
                                                   int* __restrict__ eidx, int nEdges) {
  int e = blockIdx.x * 256 + threadIdx.x;
  if (e < nEdges) {
    int pos = atomicAdd(&cursor[dst[e]], 1);
    eidx[pos] = src[e];
  }
}

// ---------------- CSR gather: agg[v] = s_in[v] * sum_{u in N_in(v)} h[u]*s_out[u] ----------------
// one node per block (blockDim.x == D): rowptr/eidx/s_out addrs are wave-uniform -> s_load
template <int D>
__global__ __launch_bounds__(D) void gather_kernel(const float* __restrict__ h,
                                                   const float* __restrict__ s_out,
                                                   const float* __restrict__ s_in,
                                                   const int* __restrict__ rowptr,
                                                   const int* __restrict__ eidx,
                                                   float* __restrict__ agg) {
  const int node = blockIdx.x;
  const int f = threadIdx.x;
  int beg = rowptr[node];
  int end = rowptr[node + 1];
  float acc = 0.0f;
  int j = beg;
  for (; j + 7 < end; j += 8) {
    int s0 = eidx[j + 0], s1 = eidx[j + 1], s2 = eidx[j + 2], s3 = eidx[j + 3];
    int s4 = eidx[j + 4], s5 = eidx[j + 5], s6 = eidx[j + 6], s7 = eidx[j + 7];
    float a0 = h[(size_t)s0 * D + f];
    float a1 = h[(size_t)s1 * D + f];
    float a2 = h[(size_t)s2 * D + f];
    float a3 = h[(size_t)s3 * D + f];
    float a4 = h[(size_t)s4 * D + f];
    float a5 = h[(size_t)s5 * D + f];
    float a6 = h[(size_t)s6 * D + f];
    float a7 = h[(size_t)s7 * D + f];
    acc += a0 * s_out[s0];
    acc += a1 * s_out[s1];
    acc += a2 * s_out[s2];
    acc += a3 * s_out[s3];
    acc += a4 * s_out[s4];
    acc += a5 * s_out[s5];
    acc += a6 * s_out[s6];
    acc += a7 * s_out[s7];
  }
  for (; j < end; j++) {
    int s = eidx[j];
    acc += h[(size_t)s * D + f] * s_out[s];
  }
  agg[(size_t)node * D + f] = acc * s_in[node];
}

// ---------------- fused GEMM: O = lrelu(A @ W + b) ----------------
// A: [M,K] row-major, W: [K,256] row-major, O: [M,256].
// 128x128 tile, 8x8 per thread (split 4+4 to keep ds_read_b128 2-way max).
template <int K>
__global__ __launch_bounds__(256) void gemm_bias_lrelu(const float* __restrict__ A,
                                                       const float* __restrict__ W,
                                                       const float* __restrict__ bias,
                                                       float* __restrict__ O, int M) {
  constexpr int BM = 128, BN = 128, BK = 32;
  __shared__ float As[BK][BM + 4];  // transposed: As[k][r]
  __shared__ float Bs[BK][BN + 4];
  const int tid = threadIdx.x;
  const int tr = tid / 16;  // 0..15
  const int tc = tid % 16;  // 0..15
  const int rowBase = blockIdx.x * BM;
  const int colBase = blockIdx.y * BN;
  float acc[8][8] = {};

  for (int k0 = 0; k0 < K; k0 += BK) {
    // load A tile 128x32: 4 passes, 8 lanes per row (32 cols via float4)
#pragma unroll
    for (int p = 0; p < 4; p++) {
      int r = p * 32 + tid / 8;
      int c4 = tid % 8;
      int gr = rowBase + r;
      if (gr >= M) gr = M - 1;  // clamp (stores are guarded)
      float4 v = *reinterpret_cast<const float4*>(&A[(size_t)gr * K + k0 + c4 * 4]);
      As[c4 * 4 + 0][r] = v.x;
      As[c4 * 4 + 1][r] = v.y;
      As[c4 * 4 + 2][r] = v.z;
      As[c4 * 4 + 3][r] = v.w;
    }
    // load B tile 32x128: 2 passes, 16 lanes per k-row (128 cols via 2x float4)
#pragma unroll
    for (int p = 0; p < 2; p++) {
      int k = p * 16 + tid / 16;
      int c = (tid % 16) * 8;
      const float* wsrc = &W[(size_t)(k0 + k) * 256 + colBase + c];
      float4 v0 = *reinterpret_cast<const float4*>(wsrc);
      float4 v1 = *reinterpret_cast<const float4*>(wsrc + 4);
      *reinterpret_cast<float4*>(&Bs[k][c]) = v0;
      *reinterpret_cast<float4*>(&Bs[k][c + 4]) = v1;
    }
    __syncthreads();
#pragma unroll
    for (int k = 0; k < BK; k++) {
      float4 a0 = *reinterpret_cast<const float4*>(&As[k][tr * 4]);
      float4 a1 = *reinterpret_cast<const float4*>(&As[k][64 + tr * 4]);
      float4 b0 = *reinterpret_cast<const float4*>(&Bs[k][tc * 4]);
      float4 b1 = *reinterpret_cast<const float4*>(&Bs[k][64 + tc * 4]);
      float a[8] = {a0.x, a0.y, a0.z, a0.w, a1.x, a1.y, a1.z, a1.w};
      float b[8] = {b0.x, b0.y, b0.z, b0.w, b1.x, b1.y, b1.z, b1.w};
#pragma unroll
      for (int i = 0; i < 8; i++)
#pragma unroll
        for (int j = 0; j < 8; j++) acc[i][j] += a[i] * b[j];
    }
    __syncthreads();
  }

  // epilogue: bias + leaky relu, guarded float4 stores (2 col-halves x 8 rows)
#pragma unroll
  for (int i = 0; i < 8; i++) {
    int row = rowBase + (i < 4 ? tr * 4 + i : 64 + tr * 4 + (i - 4));
    if (row >= M) continue;
#pragma unroll
    for (int jh = 0; jh < 2; jh++) {
      int col = colBase + jh * 64 + tc * 4;
      float4 o;
      float* po = &o.x;
#pragma unroll
      for (int j = 0; j < 4; j++) {
        float v = acc[i][jh * 4 + j] + bias[col + j];
        po[j] = v > 0.0f ? v : NEG_SLOPE * v;
      }
      *reinterpret_cast<float4*>(&O[(size_t)row * 256 + col]) = o;
    }
  }
}

// ---------------- per-graph mean pooling (graph_ids sorted) ----------------
__global__ __launch_bounds__(256) void pool_kernel(const float* __restrict__ h,
                                                   const int* __restrict__ gids,
                                                   float* __restrict__ sums,
                                                   float* __restrict__ counts, int nNodes) {
  constexpr int NB = 32;  // nodes per block
  const int f = threadIdx.x;
  const int n0 = blockIdx.x * NB;
  float acc = 0.0f;
  int cur = -1;
  int cnt = 0;
  for (int i = 0; i < NB; i++) {
    int n = n0 + i;
    if (n >= nNodes) break;
    int g = gids[n];
    if (g != cur) {
      if (cur >= 0) {
        atomicAdd(&sums[(size_t)cur * 256 + f], acc);
        if (f == 0) atomicAdd(&counts[cur], (float)cnt);
      }
      cur = g;
      acc = 0.0f;
      cnt = 0;
    }
    acc += h[(size_t)n * 256 + f];
    cnt++;
  }
  if (cur >= 0) {
    atomicAdd(&sums[(size_t)cur * 256 + f], acc);
    if (f == 0) atomicAdd(&counts[cur], (float)cnt);
  }
}

// ---------------- classifier: out = (sums/count) @ Wc + bc ----------------
__global__ __launch_bounds__(256) void cls_kernel(const float* __restrict__ sums,
                                                  const float* __restrict__ counts,
                                                  const float* __restrict__ Wc,
                                                  const float* __restrict__ bc,
                                                  float* __restrict__ out) {
  __shared__ float hg[256];
  int g = blockIdx.x;
  float invc = 1.0f / fmaxf(counts[g], 1.0f);
  hg[threadIdx.x] = sums[(size_t)g * 256 + threadIdx.x] * invc;
  __syncthreads();
  if (threadIdx.x < N_CLASSES) {
    float a = bc[threadIdx.x];
    for (int k = 0; k < 256; k++) a += hg[k] * Wc[k * N_CLASSES + threadIdx.x];
    out[g * N_CLASSES + threadIdx.x] = a;
  }
}

static constexpr size_t align1k(size_t x) { return (x + 1023) & ~(size_t)1023; }

extern "C" void kernel_launch(void* const* d_in, const int* in_sizes, int n_in,
                              void* d_out, int out_size, void* d_ws, size_t ws_size,
                              hipStream_t stream) {
  const float* x = (const float*)d_in[0];
  const int* src = (const int*)d_in[1];
  const int* dst = (const int*)d_in[2];
  const int* gids = (const int*)d_in[3];
  const float* W1 = (const float*)d_in[4];
  const float* b1 = (const float*)d_in[5];
  const float* W2 = (const float*)d_in[6];
  const float* b2 = (const float*)d_in[7];
  const float* Wc = (const float*)d_in[8];
  const float* bc = (const float*)d_in[9];
  float* out = (float*)d_out;

  // ---------------- workspace layout ----------------
  char* ws = (char*)d_ws;
  constexpr size_t OFF_CNT_IN = 0;                                      // 40000 ints
  constexpr size_t OFF_CNT_OUT = OFF_CNT_IN + (size_t)N_NODES * 4;      // 40000 ints
  constexpr size_t OFF_ROWPTR = align1k(OFF_CNT_OUT + (size_t)N_NODES * 4);  // 40001 ints
  constexpr size_t OFF_CURSOR = align1k(OFF_ROWPTR + (size_t)(N_NODES + 1) * 4);
  constexpr size_t OFF_BSUM = align1k(OFF_CURSOR + (size_t)N_NODES * 4);  // 157 ints
  constexpr size_t OFF_BOFF = align1k(OFF_BSUM + 1024);                   // 157 ints
  constexpr size_t OFF_SIN = align1k(OFF_BOFF + 1024);
  constexpr size_t OFF_SOUT = OFF_SIN + (size_t)N_NODES * 4;
  constexpr size_t OFF_PCNT = align1k(OFF_SOUT + (size_t)N_NODES * 4);  // 128 floats
  constexpr size_t OFF_SUMS = align1k(OFF_PCNT + 512);                  // 128*256 floats
  constexpr size_t OFF_EIDX = align1k(OFF_SUMS + (size_t)N_GRAPHS * 256 * 4);
  constexpr size_t OFF_AGG = align1k(OFF_EIDX + (size_t)N_EDGES * 4);
  constexpr size_t SZ_BIG = (size_t)N_NODES * 256 * 4;  // 40,960,000
  constexpr size_t OFF_H = align1k(OFF_AGG + SZ_BIG);

  int* cntIn = (int*)(ws + OFF_CNT_IN);
  int* cntOut = (int*)(ws + OFF_CNT_OUT);
  int* rowptr = (int*)(ws + OFF_ROWPTR);
  int* cursor = (int*)(ws + OFF_CURSOR);
  int* bsum = (int*)(ws + OFF_BSUM);
  int* boff = (int*)(ws + OFF_BOFF);
  float* s_in = (float*)(ws + OFF_SIN);
  float* s_out = (float*)(ws + OFF_SOUT);
  float* counts = (float*)(ws + OFF_PCNT);
  float* sums = (float*)(ws + OFF_SUMS);
  int* eidx = (int*)(ws + OFF_EIDX);
  float* agg = (float*)(ws + OFF_AGG);
  float* h = (float*)(ws + OFF_H);

  // zero: histogram counters; pool counts+sums
  hipMemsetAsync(ws + OFF_CNT_IN, 0, 2 * (size_t)N_NODES * 4, stream);
  hipMemsetAsync(ws + OFF_PCNT, 0, OFF_SUMS + (size_t)N_GRAPHS * 256 * 4 - OFF_PCNT, stream);

  // ---------------- CSR build + degree scales ----------------
  hist_kernel<<<(N_EDGES + 255) / 256, 256, 0, stream>>>(src, dst, cntOut, cntIn, N_EDGES);
  scan1_kernel<<<SCAN_BLOCKS, 256, 0, stream>>>(cntIn, rowptr, bsum);
  scan2_kernel<<<1, 256, 0, stream>>>(bsum, boff, rowptr);
  scan3_kernel<<<SCAN_BLOCKS, 256, 0, stream>>>(rowptr, boff, cursor, cntIn, cntOut, s_in, s_out);
  fill_kernel<<<(N_EDGES + 255) / 256, 256, 0, stream>>>(src, dst, cursor, eidx, N_EDGES);

  // ---------------- layer 1 ----------------
  gather_kernel<IN_DIM><<<N_NODES, IN_DIM, 0, stream>>>(x, s_out, s_in, rowptr, eidx, agg);
  {
    dim3 grid((N_NODES + 127) / 128, 256 / 128);
    gemm_bias_lrelu<IN_DIM><<<grid, 256, 0, stream>>>(agg, W1, b1, h, N_NODES);
  }

  // ---------------- layer 2 ----------------
  gather_kernel<HID_DIM><<<N_NODES, HID_DIM, 0, stream>>>(h, s_out, s_in, rowptr, eidx, agg);
  {
    dim3 grid((N_NODES + 127) / 128, 256 / 128);
    gemm_bias_lrelu<HID_DIM><<<grid, 256, 0, stream>>>(agg, W2, b2, h, N_NODES);
  }

  // ---------------- pooling + classifier ----------------
  pool_kernel<<<(N_NODES + 31) / 32, 256, 0, stream>>>(h, gids, sums, counts, N_NODES);
  cls_kernel<<<N_GRAPHS, 256, 0, stream>>>(sums, counts, Wc, bc, out);
}

// Round 7
// 411.205 us; speedup vs baseline: 1.3411x; 1.1027x over previous
//
#include <hip/hip_runtime.h>

#define N_NODES 40000
#define N_EDGES 640000
#define IN_DIM 128
#define HID_DIM 256
#define OUT_DIM 256
#define N_CLASSES 10
#define N_GRAPHS 128
#define NEG_SLOPE 0.01f

#define SCAN_BLOCKS ((N_NODES + 255) / 256)  // 157

typedef short bf16x8 __attribute__((ext_vector_type(8)));
typedef float f32x4 __attribute__((ext_vector_type(4)));

// ---- split-bf16 helpers (RNE) ----
__device__ inline unsigned short f2bf(float x) {
  unsigned u = __float_as_uint(x);
  u += 0x7fffu + ((u >> 16) & 1u);
  return (unsigned short)(u >> 16);
}
__device__ inline float bf2f(unsigned short h) {
  return __uint_as_float(((unsigned)h) << 16);
}
__device__ inline unsigned pack_split(float v) {
  unsigned short hi = f2bf(v);
  float r = v - bf2f(hi);
  unsigned short lo = f2bf(r);
  return (unsigned)hi | ((unsigned)lo << 16);
}

// ---------------- edge histogram (both directions) ----------------
__global__ __launch_bounds__(256) void hist_kernel(const int* __restrict__ src,
                                                   const int* __restrict__ dst,
                                                   int* __restrict__ cntOut,
                                                   int* __restrict__ cntIn, int nEdges) {
  int i = blockIdx.x * 256 + threadIdx.x;
  if (i < nEdges) {
    atomicAdd(&cntOut[src[i]], 1);
    atomicAdd(&cntIn[dst[i]], 1);
  }
}

// ---------------- stage 1: per-block exclusive scan + block sums ----------------
__global__ __launch_bounds__(256) void scan1_kernel(const int* __restrict__ cnt,
                                                    int* __restrict__ rowptr,
                                                    int* __restrict__ blockSums) {
  __shared__ int sm[256];
  int i = blockIdx.x * 256 + threadIdx.x;
  int v = (i < N_NODES) ? cnt[i] : 0;
  sm[threadIdx.x] = v;
  __syncthreads();
  for (int off = 1; off < 256; off <<= 1) {
    int t = (threadIdx.x >= off) ? sm[threadIdx.x - off] : 0;
    __syncthreads();
    sm[threadIdx.x] += t;
    __syncthreads();
  }
  if (i < N_NODES) rowptr[i] = sm[threadIdx.x] - v;  // exclusive within block
  if (threadIdx.x == 255) blockSums[blockIdx.x] = sm[255];
}

// ---------------- stage 2: scan block sums (157 values) ----------------
__global__ __launch_bounds__(256) void scan2_kernel(const int* __restrict__ blockSums,
                                                    int* __restrict__ blockOff,
                                                    int* __restrict__ rowptr) {
  __shared__ int sm[256];
  int tid = threadIdx.x;
  int v = (tid < SCAN_BLOCKS) ? blockSums[tid] : 0;
  sm[tid] = v;
  __syncthreads();
  for (int off = 1; off < 256; off <<= 1) {
    int t = (tid >= off) ? sm[tid - off] : 0;
    __syncthreads();
    sm[tid] += t;
    __syncthreads();
  }
  if (tid < SCAN_BLOCKS) blockOff[tid] = sm[tid] - v;  // exclusive
  if (tid == 255) rowptr[N_NODES] = sm[255];           // total edges
}

// ---------------- stage 3: add offsets; init cursor; degree scales ----------------
__global__ __launch_bounds__(256) void scan3_kernel(int* __restrict__ rowptr,
                                                    const int* __restrict__ blockOff,
                                                    int* __restrict__ cursor,
                                                    const int* __restrict__ cntIn,
                                                    const int* __restrict__ cntOut,
                                                    float* __restrict__ sIn,
                                                    float* __restrict__ sOut) {
  int i = blockIdx.x * 256 + threadIdx.x;
  if (i < N_NODES) {
    int r = rowptr[i] + blockOff[blockIdx.x];
    rowptr[i] = r;
    cursor[i] = r;
    sIn[i] = rsqrtf((float)max(cntIn[i], 1));
    sOut[i] = rsqrtf((float)max(cntOut[i], 1));
  }
}

// ---------------- fill CSR adjacency: eidx[bucket positions] = src ----------------
__global__ __launch_bounds__(256) void fill_kernel(const int* __restrict__ src,
                                                   const int* __restrict__ dst,
                                                   int* __restrict__ cursor,
                                                   int* __restrict__ eidx, int nEdges) {
  int e = blockIdx.x * 256 + threadIdx.x;
  if (e < nEdges) {
    int pos = atomicAdd(&cursor[dst[e]], 1);
    eidx[pos] = src[e];
  }
}

// ---- W split+transpose: W[K][256] fp32 -> Wt[256][K] packed (hi,lo) bf16 ----
__global__ __launch_bounds__(256) void wsplit_kernel(const float* __restrict__ W,
                                                     unsigned* __restrict__ Wt, int K) {
  int i = blockIdx.x * 256 + threadIdx.x;
  if (i < K * 256) {
    int k = i >> 8;
    int n = i & 255;
    Wt[(size_t)n * K + k] = pack_split(W[i]);
  }
}

template <int VEC> struct VecOf;
template <> struct VecOf<2> { using T = float2; using U = uint2; };
template <> struct VecOf<4> { using T = float4; using U = uint4; };

// ---------------- CSR gather: aggp[v] = split_bf16(s_in[v] * sum h[u]*s_out[u]) ----------------
// one node per 64-thread wave: rowptr/eidx/s_out addrs wave-uniform -> s_load;
// per-lane float4/float2 row reads (16/8 B) for max bytes-in-flight.
template <int D>
__global__ __launch_bounds__(64) void gather_kernel(const float* __restrict__ h,
                                                    const float* __restrict__ s_out,
                                                    const float* __restrict__ s_in,
                                                    const int* __restrict__ rowptr,
                                                    const int* __restrict__ eidx,
                                                    unsigned* __restrict__ aggp) {
  constexpr int VEC = D / 64;  // 4 (D=256) or 2 (D=128)
  using VT = typename VecOf<VEC>::T;
  using UT = typename VecOf<VEC>::U;
  const int node = blockIdx.x;
  const int f0 = threadIdx.x * VEC;
  const int beg = rowptr[node];
  const int end = rowptr[node + 1];
  float acc[VEC] = {};
  int j = beg;
  for (; j + 3 < end; j += 4) {
    int s0 = eidx[j + 0], s1 = eidx[j + 1], s2 = eidx[j + 2], s3 = eidx[j + 3];
    VT v0 = *reinterpret_cast<const VT*>(&h[(size_t)s0 * D + f0]);
    VT v1 = *reinterpret_cast<const VT*>(&h[(size_t)s1 * D + f0]);
    VT v2 = *reinterpret_cast<const VT*>(&h[(size_t)s2 * D + f0]);
    VT v3 = *reinterpret_cast<const VT*>(&h[(size_t)s3 * D + f0]);
    float c0 = s_out[s0], c1 = s_out[s1], c2 = s_out[s2], c3 = s_out[s3];
    const float* p0 = reinterpret_cast<const float*>(&v0);
    const float* p1 = reinterpret_cast<const float*>(&v1);
    const float* p2 = reinterpret_cast<const float*>(&v2);
    const float* p3 = reinterpret_cast<const float*>(&v3);
#pragma unroll
    for (int q = 0; q < VEC; q++) {
      acc[q] += p0[q] * c0;
      acc[q] += p1[q] * c1;
      acc[q] += p2[q] * c2;
      acc[q] += p3[q] * c3;
    }
  }
  for (; j < end; j++) {
    int s = eidx[j];
    VT v = *reinterpret_cast<const VT*>(&h[(size_t)s * D + f0]);
    float c = s_out[s];
    const float* p = reinterpret_cast<const float*>(&v);
#pragma unroll
    for (int q = 0; q < VEC; q++) acc[q] += p[q] * c;
  }
  float si = s_in[node];
  UT o;
  unsigned* po = reinterpret_cast<unsigned*>(&o);
#pragma unroll
  for (int q = 0; q < VEC; q++) po[q] = pack_split(acc[q] * si);
  *reinterpret_cast<UT*>(&aggp[(size_t)node * D + f0]) = o;
}

// ---------------- MFMA GEMM: O = lrelu(A @ W + b), split-bf16 3-product ----------------
// Apk: [M][K] packed (hi,lo); Wt: [256][K] packed; O: [M,256] fp32.
// 128x128 tile, BK=32, 4 waves (2x2), each wave 64x64 via 4x4 16x16x32 MFMAs x3 products.
template <int K>
__global__ __launch_bounds__(256) void gemm_mfma_bias_lrelu(const unsigned* __restrict__ Apk,
                                                            const unsigned* __restrict__ Wt,
                                                            const float* __restrict__ bias,
                                                            float* __restrict__ O, int M) {
  constexpr int BM = 128, BN = 128, BK = 32;
  constexpr int LDK = BK + 8;  // 40 ushorts/row: frag b128 reads 2-way bank alias (free)
  __shared__ unsigned short Ah[BM][LDK], Al[BM][LDK];
  __shared__ unsigned short Bh[BN][LDK], Bl[BN][LDK];
  const int tid = threadIdx.x;
  const int lane = tid & 63;
  const int wave = tid >> 6;
  const int wr = wave >> 1, wc = wave & 1;  // 2x2 wave grid, 64x64 each
  const int rowBase = blockIdx.x * BM;
  const int colBase = blockIdx.y * BN;
  const int g = lane >> 4;    // 0..3  -> k-group / C row-group
  const int r16 = lane & 15;  // fragment row/col

  f32x4 acc[4][4] = {};

  for (int k0 = 0; k0 < K; k0 += BK) {
    // stage A: 128x32 packed elems, 4 passes x 256 thr x 4 elems (uint4)
#pragma unroll
    for (int p = 0; p < 4; p++) {
      int e = (p * 256 + tid) * 4;
      int r = e >> 5;
      int kc = e & 31;
      int gr = rowBase + r;
      if (gr >= M) gr = M - 1;  // clamp; stores guarded
      uint4 v = *reinterpret_cast<const uint4*>(&Apk[(size_t)gr * K + k0 + kc]);
      *reinterpret_cast<unsigned*>(&Ah[r][kc]) = (v.x & 0xffffu) | (v.y << 16);
      *reinterpret_cast<unsigned*>(&Ah[r][kc + 2]) = (v.z & 0xffffu) | (v.w << 16);
      *reinterpret_cast<unsigned*>(&Al[r][kc]) = (v.x >> 16) | (v.y & 0xffff0000u);
      *reinterpret_cast<unsigned*>(&Al[r][kc + 2]) = (v.z >> 16) | (v.w & 0xffff0000u);
    }
    // stage B: Wt rows are n (K-major), same geometry
#pragma unroll
    for (int p = 0; p < 4; p++) {
      int e = (p * 256 + tid) * 4;
      int n = e >> 5;
      int kc = e & 31;
      uint4 v = *reinterpret_cast<const uint4*>(&Wt[(size_t)(colBase + n) * K + k0 + kc]);
      *reinterpret_cast<unsigned*>(&Bh[n][kc]) = (v.x & 0xffffu) | (v.y << 16);
      *reinterpret_cast<unsigned*>(&Bh[n][kc + 2]) = (v.z & 0xffffu) | (v.w << 16);
      *reinterpret_cast<unsigned*>(&Bl[n][kc]) = (v.x >> 16) | (v.y & 0xffff0000u);
      *reinterpret_cast<unsigned*>(&Bl[n][kc + 2]) = (v.z >> 16) | (v.w & 0xffff0000u);
    }
    __syncthreads();

    // fragments: A[row=lane&15][k=(lane>>4)*8+j], B[k][col=lane&15]
    bf16x8 afh[4], afl[4], bfh[4], bfl[4];
#pragma unroll
    for (int mf = 0; mf < 4; mf++) {
      afh[mf] = *reinterpret_cast<const bf16x8*>(&Ah[wr * 64 + mf * 16 + r16][g * 8]);
      afl[mf] = *reinterpret_cast<const bf16x8*>(&Al[wr * 64 + mf * 16 + r16][g * 8]);
    }
#pragma unroll
    for (int nf = 0; nf < 4; nf++) {
      bfh[nf] = *reinterpret_cast<const bf16x8*>(&Bh[wc * 64 + nf * 16 + r16][g * 8]);
      bfl[nf] = *reinterpret_cast<const bf16x8*>(&Bl[wc * 64 + nf * 16 + r16][g * 8]);
    }
#pragma unroll
    for (int mf = 0; mf < 4; mf++)
#pragma unroll
      for (int nf = 0; nf < 4; nf++) {
        acc[mf][nf] = __builtin_amdgcn_mfma_f32_16x16x32_bf16(afh[mf], bfh[nf], acc[mf][nf], 0, 0, 0);
        acc[mf][nf] = __builtin_amdgcn_mfma_f32_16x16x32_bf16(afh[mf], bfl[nf], acc[mf][nf], 0, 0, 0);
        acc[mf][nf] = __builtin_amdgcn_mfma_f32_16x16x32_bf16(afl[mf], bfh[nf], acc[mf][nf], 0, 0, 0);
      }
    __syncthreads();
  }

  // epilogue: C/D map col=lane&15, row=(lane>>4)*4+reg
#pragma unroll
  for (int mf = 0; mf < 4; mf++)
#pragma unroll
    for (int nf = 0; nf < 4; nf++) {
      int col = colBase + wc * 64 + nf * 16 + r16;
      float bv = bias[col];
#pragma unroll
      for (int j = 0; j < 4; j++) {
        int row = rowBase + wr * 64 + mf * 16 + g * 4 + j;
        if (row < M) {
          float v = acc[mf][nf][j] + bv;
          O[(size_t)row * 256 + col] = v > 0.0f ? v : NEG_SLOPE * v;
        }
      }
    }
}

// ---------------- per-graph mean pooling (graph_ids sorted) ----------------
__global__ __launch_bounds__(256) void pool_kernel(const float* __restrict__ h,
                                                   const int* __restrict__ gids,
                                                   float* __restrict__ sums,
                                                   float* __restrict__ counts, int nNodes) {
  constexpr int NB = 32;  // nodes per block
  const int f = threadIdx.x;
  const int n0 = blockIdx.x * NB;
  float acc = 0.0f;
  int cur = -1;
  int cnt = 0;
  for (int i = 0; i < NB; i++) {
    int n = n0 + i;
    if (n >= nNodes) break;
    int g = gids[n];
    if (g != cur) {
      if (cur >= 0) {
        atomicAdd(&sums[(size_t)cur * 256 + f], acc);
        if (f == 0) atomicAdd(&counts[cur], (float)cnt);
      }
      cur = g;
      acc = 0.0f;
      cnt = 0;
    }
    acc += h[(size_t)n * 256 + f];
    cnt++;
  }
  if (cur >= 0) {
    atomicAdd(&sums[(size_t)cur * 256 + f], acc);
    if (f == 0) atomicAdd(&counts[cur], (float)cnt);
  }
}

// ---------------- classifier: out = (sums/count) @ Wc + bc ----------------
__global__ __launch_bounds__(256) void cls_kernel(const float* __restrict__ sums,
                                                  const float* __restrict__ counts,
                                                  const float* __restrict__ Wc,
                                                  const float* __restrict__ bc,
                                                  float* __restrict__ out) {
  __shared__ float hg[256];
  int g = blockIdx.x;
  float invc = 1.0f / fmaxf(counts[g], 1.0f);
  hg[threadIdx.x] = sums[(size_t)g * 256 + threadIdx.x] * invc;
  __syncthreads();
  if (threadIdx.x < N_CLASSES) {
    float a = bc[threadIdx.x];
    for (int k = 0; k < 256; k++) a += hg[k] * Wc[k * N_CLASSES + threadIdx.x];
    out[g * N_CLASSES + threadIdx.x] = a;
  }
}

static constexpr size_t align1k(size_t x) { return (x + 1023) & ~(size_t)1023; }

extern "C" void kernel_launch(void* const* d_in, const int* in_sizes, int n_in,
                              void* d_out, int out_size, void* d_ws, size_t ws_size,
                              hipStream_t stream) {
  const float* x = (const float*)d_in[0];
  const int* src = (const int*)d_in[1];
  const int* dst = (const int*)d_in[2];
  const int* gids = (const int*)d_in[3];
  const float* W1 = (const float*)d_in[4];
  const float* b1 = (const float*)d_in[5];
  const float* W2 = (const float*)d_in[6];
  const float* b2 = (const float*)d_in[7];
  const float* Wc = (const float*)d_in[8];
  const float* bc = (const float*)d_in[9];
  float* out = (float*)d_out;

  // ---------------- workspace layout ----------------
  char* ws = (char*)d_ws;
  constexpr size_t OFF_CNT_IN = 0;                                      // 40000 ints
  constexpr size_t OFF_CNT_OUT = OFF_CNT_IN + (size_t)N_NODES * 4;      // 40000 ints
  constexpr size_t OFF_ROWPTR = align1k(OFF_CNT_OUT + (size_t)N_NODES * 4);  // 40001 ints
  constexpr size_t OFF_CURSOR = align1k(OFF_ROWPTR + (size_t)(N_NODES + 1) * 4);
  constexpr size_t OFF_BSUM = align1k(OFF_CURSOR + (size_t)N_NODES * 4);  // 157 ints
  constexpr size_t OFF_BOFF = align1k(OFF_BSUM + 1024);                   // 157 ints
  constexpr size_t OFF_SIN = align1k(OFF_BOFF + 1024);
  constexpr size_t OFF_SOUT = OFF_SIN + (size_t)N_NODES * 4;
  constexpr size_t OFF_PCNT = align1k(OFF_SOUT + (size_t)N_NODES * 4);  // 128 floats
  constexpr size_t OFF_SUMS = align1k(OFF_PCNT + 512);                  // 128*256 floats
  constexpr size_t OFF_EIDX = align1k(OFF_SUMS + (size_t)N_GRAPHS * 256 * 4);
  constexpr size_t OFF_AGG = align1k(OFF_EIDX + (size_t)N_EDGES * 4);
  constexpr size_t SZ_BIG = (size_t)N_NODES * 256 * 4;  // 40,960,000
  constexpr size_t OFF_H = align1k(OFF_AGG + SZ_BIG);
  constexpr size_t OFF_WT1 = align1k(OFF_H + SZ_BIG);                   // 256x128 uint
  constexpr size_t OFF_WT2 = align1k(OFF_WT1 + 256 * 128 * 4);          // 256x256 uint

  int* cntIn = (int*)(ws + OFF_CNT_IN);
  int* cntOut = (int*)(ws + OFF_CNT_OUT);
  int* rowptr = (int*)(ws + OFF_ROWPTR);
  int* cursor = (int*)(ws + OFF_CURSOR);
  int* bsum = (int*)(ws + OFF_BSUM);
  int* boff = (int*)(ws + OFF_BOFF);
  float* s_in = (float*)(ws + OFF_SIN);
  float* s_out = (float*)(ws + OFF_SOUT);
  float* counts = (float*)(ws + OFF_PCNT);
  float* sums = (float*)(ws + OFF_SUMS);
  int* eidx = (int*)(ws + OFF_EIDX);
  unsigned* aggp = (unsigned*)(ws + OFF_AGG);
  float* h = (float*)(ws + OFF_H);
  unsigned* Wt1 = (unsigned*)(ws + OFF_WT1);
  unsigned* Wt2 = (unsigned*)(ws + OFF_WT2);

  // zero: histogram counters; pool counts+sums
  hipMemsetAsync(ws + OFF_CNT_IN, 0, 2 * (size_t)N_NODES * 4, stream);
  hipMemsetAsync(ws + OFF_PCNT, 0, OFF_SUMS + (size_t)N_GRAPHS * 256 * 4 - OFF_PCNT, stream);

  // ---------------- CSR build + degree scales + W splits ----------------
  hist_kernel<<<(N_EDGES + 255) / 256, 256, 0, stream>>>(src, dst, cntOut, cntIn, N_EDGES);
  scan1_kernel<<<SCAN_BLOCKS, 256, 0, stream>>>(cntIn, rowptr, bsum);
  scan2_kernel<<<1, 256, 0, stream>>>(bsum, boff, rowptr);
  scan3_kernel<<<SCAN_BLOCKS, 256, 0, stream>>>(rowptr, boff, cursor, cntIn, cntOut, s_in, s_out);
  fill_kernel<<<(N_EDGES + 255) / 256, 256, 0, stream>>>(src, dst, cursor, eidx, N_EDGES);
  wsplit_kernel<<<(IN_DIM * 256 + 255) / 256, 256, 0, stream>>>(W1, Wt1, IN_DIM);
  wsplit_kernel<<<(HID_DIM * 256 + 255) / 256, 256, 0, stream>>>(W2, Wt2, HID_DIM);

  dim3 ggrid((N_NODES + 127) / 128, 2);

  // ---------------- layer 1 ----------------
  gather_kernel<IN_DIM><<<N_NODES, 64, 0, stream>>>(x, s_out, s_in, rowptr, eidx, aggp);
  gemm_mfma_bias_lrelu<IN_DIM><<<ggrid, 256, 0, stream>>>(aggp, Wt1, b1, h, N_NODES);

  // ---------------- layer 2 ----------------
  gather_kernel<HID_DIM><<<N_NODES, 64, 0, stream>>>(h, s_out, s_in, rowptr, eidx, aggp);
  gemm_mfma_bias_lrelu<HID_DIM><<<ggrid, 256, 0, stream>>>(aggp, Wt2, b2, h, N_NODES);

  // ---------------- pooling + classifier ----------------
  pool_kernel<<<(N_NODES + 31) / 32, 256, 0, stream>>>(h, gids, sums, counts, N_NODES);
  cls_kernel<<<N_GRAPHS, 256, 0, stream>>>(sums, counts, Wc, bc, out);
}

// Round 9
// 410.575 us; speedup vs baseline: 1.3431x; 1.0015x over previous
//
#include <hip/hip_runtime.h>

#define N_NODES 40000
#define N_EDGES 640000
#define IN_DIM 128
#define HID_DIM 256
#define OUT_DIM 256
#define N_CLASSES 10
#define N_GRAPHS 128
#define NEG_SLOPE 0.01f

#define SCAN_BLOCKS ((N_NODES + 255) / 256)  // 157

typedef short bf16x8 __attribute__((ext_vector_type(8)));
typedef float f32x4 __attribute__((ext_vector_type(4)));

// ---- split-bf16 helpers (RNE) ----
__device__ inline unsigned short f2bf(float x) {
  unsigned u = __float_as_uint(x);
  u += 0x7fffu + ((u >> 16) & 1u);
  return (unsigned short)(u >> 16);
}
__device__ inline float bf2f(unsigned short h) {
  return __uint_as_float(((unsigned)h) << 16);
}
__device__ inline unsigned pack_split(float v) {
  unsigned short hi = f2bf(v);
  float r = v - bf2f(hi);
  unsigned short lo = f2bf(r);
  return (unsigned)hi | ((unsigned)lo << 16);
}

// ---------------- edge histogram (both directions) ----------------
__global__ __launch_bounds__(256) void hist_kernel(const int* __restrict__ src,
                                                   const int* __restrict__ dst,
                                                   int* __restrict__ cntOut,
                                                   int* __restrict__ cntIn, int nEdges) {
  int i = blockIdx.x * 256 + threadIdx.x;
  if (i < nEdges) {
    atomicAdd(&cntOut[src[i]], 1);
    atomicAdd(&cntIn[dst[i]], 1);
  }
}

// ---------------- stage 1: per-block exclusive scan + block sums ----------------
__global__ __launch_bounds__(256) void scan1_kernel(const int* __restrict__ cnt,
                                                    int* __restrict__ rowptr,
                                                    int* __restrict__ blockSums) {
  __shared__ int sm[256];
  int i = blockIdx.x * 256 + threadIdx.x;
  int v = (i < N_NODES) ? cnt[i] : 0;
  sm[threadIdx.x] = v;
  __syncthreads();
  for (int off = 1; off < 256; off <<= 1) {
    int t = (threadIdx.x >= off) ? sm[threadIdx.x - off] : 0;
    __syncthreads();
    sm[threadIdx.x] += t;
    __syncthreads();
  }
  if (i < N_NODES) rowptr[i] = sm[threadIdx.x] - v;  // exclusive within block
  if (threadIdx.x == 255) blockSums[blockIdx.x] = sm[255];
}

// ---------------- stage 2: scan block sums (157 values) ----------------
__global__ __launch_bounds__(256) void scan2_kernel(const int* __restrict__ blockSums,
                                                    int* __restrict__ blockOff,
                                                    int* __restrict__ rowptr) {
  __shared__ int sm[256];
  int tid = threadIdx.x;
  int v = (tid < SCAN_BLOCKS) ? blockSums[tid] : 0;
  sm[tid] = v;
  __syncthreads();
  for (int off = 1; off < 256; off <<= 1) {
    int t = (tid >= off) ? sm[tid - off] : 0;
    __syncthreads();
    sm[tid] += t;
    __syncthreads();
  }
  if (tid < SCAN_BLOCKS) blockOff[tid] = sm[tid] - v;  // exclusive
  if (tid == 255) rowptr[N_NODES] = sm[255];           // total edges
}

// ---------------- stage 3: add offsets; init cursor; degree scales; zero pool buffers ----------------
__global__ __launch_bounds__(256) void scan3_kernel(int* __restrict__ rowptr,
                                                    const int* __restrict__ blockOff,
                                                    int* __restrict__ cursor,
                                                    const int* __restrict__ cntIn,
                                                    const int* __restrict__ cntOut,
                                                    float* __restrict__ sIn,
                                                    float* __restrict__ sOut,
                                                    float* __restrict__ poolZero, int nZero) {
  int i = blockIdx.x * 256 + threadIdx.x;
  if (i < N_NODES) {
    int r = rowptr[i] + blockOff[blockIdx.x];
    rowptr[i] = r;
    cursor[i] = r;
    sIn[i] = rsqrtf((float)max(cntIn[i], 1));
    sOut[i] = rsqrtf((float)max(cntOut[i], 1));
  }
  if (i < nZero) poolZero[i] = 0.0f;
}

// ---------------- fill CSR adjacency: eidx[bucket positions] = src ----------------
__global__ __launch_bounds__(256) void fill_kernel(const int* __restrict__ src,
                                                   const int* __restrict__ dst,
                                                   int* __restrict__ cursor,
                                                   int* __restrict__ eidx, int nEdges) {
  int e = blockIdx.x * 256 + threadIdx.x;
  if (e < nEdges) {
    int pos = atomicAdd(&cursor[dst[e]], 1);
    eidx[pos] = src[e];
  }
}

// ---- W split+transpose (both weights, one launch) ----
__global__ __launch_bounds__(256) void wsplit_kernel(const float* __restrict__ W1,
                                                     unsigned* __restrict__ Wt1,
                                                     const float* __restrict__ W2,
                                                     unsigned* __restrict__ Wt2) {
  int i = blockIdx.x * 256 + threadIdx.x;
  constexpr int N1 = IN_DIM * 256;
  if (i < N1) {
    int k = i >> 8;
    int n = i & 255;
    Wt1[(size_t)n * IN_DIM + k] = pack_split(W1[i]);
  } else {
    int j = i - N1;
    if (j < HID_DIM * 256) {
      int k = j >> 8;
      int n = j & 255;
      Wt2[(size_t)n * HID_DIM + k] = pack_split(W2[j]);
    }
  }
}

template <int VEC> struct VecOf;
template <> struct VecOf<2> { using T = float2; using U = uint2; };
template <> struct VecOf<4> { using T = float4; using U = uint4; };

// ---------------- CSR gather: aggp[v] = split_bf16(s_in[v] * sum h[u]*s_out[u]) ----------------
// 256-thread block = 4 waves = 4 nodes; node idx pinned wave-uniform (s_load path);
// 8-deep edge unroll -> 128 B/lane in flight.
template <int D>
__global__ __launch_bounds__(256) void gather_kernel(const float* __restrict__ h,
                                                     const float* __restrict__ s_out,
                                                     const float* __restrict__ s_in,
                                                     const int* __restrict__ rowptr,
                                                     const int* __restrict__ eidx,
                                                     unsigned* __restrict__ aggp) {
  constexpr int VEC = D / 64;  // 4 (D=256) or 2 (D=128)
  using VT = typename VecOf<VEC>::T;
  using UT = typename VecOf<VEC>::U;
  const int node = __builtin_amdgcn_readfirstlane(blockIdx.x * 4 + (threadIdx.x >> 6));
  const int lane = threadIdx.x & 63;
  const int f0 = lane * VEC;
  const int beg = rowptr[node];
  const int end = rowptr[node + 1];
  float acc[VEC] = {};
  int j = beg;
  for (; j + 7 < end; j += 8) {
    int s[8];
#pragma unroll
    for (int u = 0; u < 8; u++) s[u] = eidx[j + u];
    VT v[8];
#pragma unroll
    for (int u = 0; u < 8; u++) v[u] = *reinterpret_cast<const VT*>(&h[(size_t)s[u] * D + f0]);
    float c[8];
#pragma unroll
    for (int u = 0; u < 8; u++) c[u] = s_out[s[u]];
#pragma unroll
    for (int u = 0; u < 8; u++) {
      const float* p = reinterpret_cast<const float*>(&v[u]);
#pragma unroll
      for (int q = 0; q < VEC; q++) acc[q] += p[q] * c[u];
    }
  }
  for (; j < end; j++) {
    int s = eidx[j];
    VT v = *reinterpret_cast<const VT*>(&h[(size_t)s * D + f0]);
    float c = s_out[s];
    const float* p = reinterpret_cast<const float*>(&v);
#pragma unroll
    for (int q = 0; q < VEC; q++) acc[q] += p[q] * c;
  }
  float si = s_in[node];
  UT o;
  unsigned* po = reinterpret_cast<unsigned*>(&o);
#pragma unroll
  for (int q = 0; q < VEC; q++) po[q] = pack_split(acc[q] * si);
  *reinterpret_cast<UT*>(&aggp[(size_t)node * D + f0]) = o;
}

// ---------------- MFMA GEMM: O = lrelu(A @ W + b), split-bf16 3-product ----------------
// Apk: [M][K] packed (hi,lo); Wt: [256][K] packed; O: [M,256] fp32.
// 128x128 tile, BK=32, 4 waves (2x2), each wave 64x64 via 4x4 16x16x32 MFMAs x3 products.
template <int K>
__global__ __launch_bounds__(256) void gemm_mfma_bias_lrelu(const unsigned* __restrict__ Apk,
                                                            const unsigned* __restrict__ Wt,
                                                            const float* __restrict__ bias,
                                                            float* __restrict__ O, int M) {
  constexpr int BM = 128, BN = 128, BK = 32;
  constexpr int LDK = BK + 8;  // 40 ushorts/row: frag b128 reads 2-way bank alias (free)
  __shared__ unsigned short Ah[BM][LDK], Al[BM][LDK];
  __shared__ unsigned short Bh[BN][LDK], Bl[BN][LDK];
  const int tid = threadIdx.x;
  const int lane = tid & 63;
  const int wave = tid >> 6;
  const int wr = wave >> 1, wc = wave & 1;  // 2x2 wave grid, 64x64 each
  const int rowBase = blockIdx.x * BM;
  const int colBase = blockIdx.y * BN;
  const int g = lane >> 4;    // 0..3  -> k-group / C row-group
  const int r16 = lane & 15;  // fragment row/col

  f32x4 acc[4][4] = {};

  for (int k0 = 0; k0 < K; k0 += BK) {
    // stage A: 128x32 packed elems, 4 passes x 256 thr x 4 elems (uint4)
#pragma unroll
    for (int p = 0; p < 4; p++) {
      int e = (p * 256 + tid) * 4;
      int r = e >> 5;
      int kc = e & 31;
      int gr = rowBase + r;
      if (gr >= M) gr = M - 1;  // clamp; stores guarded
      uint4 v = *reinterpret_cast<const uint4*>(&Apk[(size_t)gr * K + k0 + kc]);
      *reinterpret_cast<unsigned*>(&Ah[r][kc]) = (v.x & 0xffffu) | (v.y << 16);
      *reinterpret_cast<unsigned*>(&Ah[r][kc + 2]) = (v.z & 0xffffu) | (v.w << 16);
      *reinterpret_cast<unsigned*>(&Al[r][kc]) = (v.x >> 16) | (v.y & 0xffff0000u);
      *reinterpret_cast<unsigned*>(&Al[r][kc + 2]) = (v.z >> 16) | (v.w & 0xffff0000u);
    }
    // stage B: Wt rows are n (K-major), same geometry
#pragma unroll
    for (int p = 0; p < 4; p++) {
      int e = (p * 256 + tid) * 4;
      int n = e >> 5;
      int kc = e & 31;
      uint4 v = *reinterpret_cast<const uint4*>(&Wt[(size_t)(colBase + n) * K + k0 + kc]);
      *reinterpret_cast<unsigned*>(&Bh[n][kc]) = (v.x & 0xffffu) | (v.y << 16);
      *reinterpret_cast<unsigned*>(&Bh[n][kc + 2]) = (v.z & 0xffffu) | (v.w << 16);
      *reinterpret_cast<unsigned*>(&Bl[n][kc]) = (v.x >> 16) | (v.y & 0xffff0000u);
      *reinterpret_cast<unsigned*>(&Bl[n][kc + 2]) = (v.z >> 16) | (v.w & 0xffff0000u);
    }
    __syncthreads();

    // fragments: A[row=lane&15][k=(lane>>4)*8+j], B[k][col=lane&15]
    bf16x8 afh[4], afl[4], bfh[4], bfl[4];
#pragma unroll
    for (int mf = 0; mf < 4; mf++) {
      afh[mf] = *reinterpret_cast<const bf16x8*>(&Ah[wr * 64 + mf * 16 + r16][g * 8]);
      afl[mf] = *reinterpret_cast<const bf16x8*>(&Al[wr * 64 + mf * 16 + r16][g * 8]);
    }
#pragma unroll
    for (int nf = 0; nf < 4; nf++) {
      bfh[nf] = *reinterpret_cast<const bf16x8*>(&Bh[wc * 64 + nf * 16 + r16][g * 8]);
      bfl[nf] = *reinterpret_cast<const bf16x8*>(&Bl[wc * 64 + nf * 16 + r16][g * 8]);
    }
#pragma unroll
    for (int mf = 0; mf < 4; mf++)
#pragma unroll
      for (int nf = 0; nf < 4; nf++) {
        acc[mf][nf] = __builtin_amdgcn_mfma_f32_16x16x32_bf16(afh[mf], bfh[nf], acc[mf][nf], 0, 0, 0);
        acc[mf][nf] = __builtin_amdgcn_mfma_f32_16x16x32_bf16(afh[mf], bfl[nf], acc[mf][nf], 0, 0, 0);
        acc[mf][nf] = __builtin_amdgcn_mfma_f32_16x16x32_bf16(afl[mf], bfh[nf], acc[mf][nf], 0, 0, 0);
      }
    __syncthreads();
  }

  // epilogue: C/D map col=lane&15, row=(lane>>4)*4+reg
#pragma unroll
  for (int mf = 0; mf < 4; mf++)
#pragma unroll
    for (int nf = 0; nf < 4; nf++) {
      int col = colBase + wc * 64 + nf * 16 + r16;
      float bv = bias[col];
#pragma unroll
      for (int j = 0; j < 4; j++) {
        int row = rowBase + wr * 64 + mf * 16 + g * 4 + j;
        if (row < M) {
          float v = acc[mf][nf][j] + bv;
          O[(size_t)row * 256 + col] = v > 0.0f ? v : NEG_SLOPE * v;
        }
      }
    }
}

// ---------------- per-graph mean pooling (graph_ids sorted) ----------------
// one wave per block; lane reads float4 -> full 1KB row per instruction
__global__ __launch_bounds__(64) void pool_kernel(const float* __restrict__ h,
                                                  const int* __restrict__ gids,
                                                  float* __restrict__ sums,
                                                  float* __restrict__ counts, int nNodes) {
  constexpr int NB = 32;  // nodes per block
  const int lane = threadIdx.x;
  const int n0 = blockIdx.x * NB;
  float4 acc = {0.0f, 0.0f, 0.0f, 0.0f};
  int cur = -1;
  int cnt = 0;
  for (int i = 0; i < NB; i++) {
    int n = n0 + i;
    if (n >= nNodes) break;
    int g = gids[n];
    if (g != cur) {
      if (cur >= 0) {
        float* sp = &sums[(size_t)cur * 256 + lane * 4];
        atomicAdd(sp + 0, acc.x);
        atomicAdd(sp + 1, acc.y);
        atomicAdd(sp + 2, acc.z);
        atomicAdd(sp + 3, acc.w);
        if (lane == 0) atomicAdd(&counts[cur], (float)cnt);
      }
      cur = g;
      acc = {0.0f, 0.0f, 0.0f, 0.0f};
      cnt = 0;
    }
    float4 v = *reinterpret_cast<const float4*>(&h[(size_t)n * 256 + lane * 4]);
    acc.x += v.x;
    acc.y += v.y;
    acc.z += v.z;
    acc.w += v.w;
    cnt++;
  }
  if (cur >= 0) {
    float* sp = &sums[(size_t)cur * 256 + lane * 4];
    atomicAdd(sp + 0, acc.x);
    atomicAdd(sp + 1, acc.y);
    atomicAdd(sp + 2, acc.z);
    atomicAdd(sp + 3, acc.w);
    if (lane == 0) atomicAdd(&counts[cur], (float)cnt);
  }
}

// ---------------- classifier: out = (sums/count) @ Wc + bc ----------------
__global__ __launch_bounds__(256) void cls_kernel(const float* __restrict__ sums,
                                                  const float* __restrict__ counts,
                                                  const float* __restrict__ Wc,
                                                  const float* __restrict__ bc,
                                                  float* __restrict__ out) {
  __shared__ float hg[256];
  int g = blockIdx.x;
  float invc = 1.0f / fmaxf(counts[g], 1.0f);
  hg[threadIdx.x] = sums[(size_t)g * 256 + threadIdx.x] * invc;
  __syncthreads();
  if (threadIdx.x < N_CLASSES) {
    float a = bc[threadIdx.x];
    for (int k = 0; k < 256; k++) a += hg[k] * Wc[k * N_CLASSES + threadIdx.x];
    out[g * N_CLASSES + threadIdx.x] = a;
  }
}

static constexpr size_t align1k(size_t x) { return (x + 1023) & ~(size_t)1023; }

extern "C" void kernel_launch(void* const* d_in, const int* in_sizes, int n_in,
                              void* d_out, int out_size, void* d_ws, size_t ws_size,
                              hipStream_t stream) {
  const float* x = (const float*)d_in[0];
  const int* src = (const int*)d_in[1];
  const int* dst = (const int*)d_in[2];
  const int* gids = (const int*)d_in[3];
  const float* W1 = (const float*)d_in[4];
  const float* b1 = (const float*)d_in[5];
  const float* W2 = (const float*)d_in[6];
  const float* b2 = (const float*)d_in[7];
  const float* Wc = (const float*)d_in[8];
  const float* bc = (const float*)d_in[9];
  float* out = (float*)d_out;

  // ---------------- workspace layout ----------------
  char* ws = (char*)d_ws;
  constexpr size_t OFF_CNT_IN = 0;                                      // 40000 ints
  constexpr size_t OFF_CNT_OUT = OFF_CNT_IN + (size_t)N_NODES * 4;      // 40000 ints
  constexpr size_t OFF_ROWPTR = align1k(OFF_CNT_OUT + (size_t)N_NODES * 4);  // 40001 ints
  constexpr size_t OFF_CURSOR = align1k(OFF_ROWPTR + (size_t)(N_NODES + 1) * 4);
  constexpr size_t OFF_BSUM = align1k(OFF_CURSOR + (size_t)N_NODES * 4);  // 157 ints
  constexpr size_t OFF_BOFF = align1k(OFF_BSUM + 1024);                   // 157 ints
  constexpr size_t OFF_SIN = align1k(OFF_BOFF + 1024);
  constexpr size_t OFF_SOUT = OFF_SIN + (size_t)N_NODES * 4;
  constexpr size_t OFF_PCNT = align1k(OFF_SOUT + (size_t)N_NODES * 4);  // 128 floats
  constexpr size_t OFF_SUMS = align1k(OFF_PCNT + 512);                  // 128*256 floats
  constexpr size_t OFF_EIDX = align1k(OFF_SUMS + (size_t)N_GRAPHS * 256 * 4);
  constexpr size_t OFF_AGG = align1k(OFF_EIDX + (size_t)N_EDGES * 4);
  constexpr size_t SZ_BIG = (size_t)N_NODES * 256 * 4;  // 40,960,000
  constexpr size_t OFF_H = align1k(OFF_AGG + SZ_BIG);
  constexpr size_t OFF_WT1 = align1k(OFF_H + SZ_BIG);                   // 256x128 uint
  constexpr size_t OFF_WT2 = align1k(OFF_WT1 + 256 * 128 * 4);          // 256x256 uint

  int* cntIn = (int*)(ws + OFF_CNT_IN);
  int* cntOut = (int*)(ws + OFF_CNT_OUT);
  int* rowptr = (int*)(ws + OFF_ROWPTR);
  int* cursor = (int*)(ws + OFF_CURSOR);
  int* bsum = (int*)(ws + OFF_BSUM);
  int* boff = (int*)(ws + OFF_BOFF);
  float* s_in = (float*)(ws + OFF_SIN);
  float* s_out = (float*)(ws + OFF_SOUT);
  float* counts = (float*)(ws + OFF_PCNT);
  float* sums = (float*)(ws + OFF_SUMS);
  int* eidx = (int*)(ws + OFF_EIDX);
  unsigned* aggp = (unsigned*)(ws + OFF_AGG);
  float* h = (float*)(ws + OFF_H);
  unsigned* Wt1 = (unsigned*)(ws + OFF_WT1);
  unsigned* Wt2 = (unsigned*)(ws + OFF_WT2);

  // zero: histogram counters (pool counts+sums zeroed inside scan3)
  hipMemsetAsync(ws + OFF_CNT_IN, 0, 2 * (size_t)N_NODES * 4, stream);

  // number of floats to zero starting at OFF_PCNT (covers counts pad + sums)
  const int nZero = (int)((OFF_SUMS - OFF_PCNT) / 4 + (size_t)N_GRAPHS * 256);

  // ---------------- CSR build + degree scales + W splits ----------------
  hist_kernel<<<(N_EDGES + 255) / 256, 256, 0, stream>>>(src, dst, cntOut, cntIn, N_EDGES);
  scan1_kernel<<<SCAN_BLOCKS, 256, 0, stream>>>(cntIn, rowptr, bsum);
  scan2_kernel<<<1, 256, 0, stream>>>(bsum, boff, rowptr);
  scan3_kernel<<<SCAN_BLOCKS, 256, 0, stream>>>(rowptr, boff, cursor, cntIn, cntOut, s_in, s_out,
                                                counts, nZero);
  fill_kernel<<<(N_EDGES + 255) / 256, 256, 0, stream>>>(src, dst, cursor, eidx, N_EDGES);
  wsplit_kernel<<<((IN_DIM + HID_DIM) * 256 + 255) / 256, 256, 0, stream>>>(W1, Wt1, W2, Wt2);

  dim3 ggrid((N_NODES + 127) / 128, 2);

  // ---------------- layer 1 ----------------
  gather_kernel<IN_DIM><<<N_NODES / 4, 256, 0, stream>>>(x, s_out, s_in, rowptr, eidx, aggp);
  gemm_mfma_bias_lrelu<IN_DIM><<<ggrid, 256, 0, stream>>>(aggp, Wt1, b1, h, N_NODES);

  // ---------------- layer 2 ----------------
  gather_kernel<HID_DIM><<<N_NODES / 4, 256, 0, stream>>>(h, s_out, s_in, rowptr, eidx, aggp);
  gemm_mfma_bias_lrelu<HID_DIM><<<ggrid, 256, 0, stream>>>(aggp, Wt2, b2, h, N_NODES);

  // ---------------- pooling + classifier ----------------
  pool_kernel<<<(N_NODES + 31) / 32, 64, 0, stream>>>(h, gids, sums, counts, N_NODES);
  cls_kernel<<<N_GRAPHS, 256, 0, stream>>>(sums, counts, Wc, bc, out);
}

// Round 10
// 361.413 us; speedup vs baseline: 1.5258x; 1.1360x over previous
//
#include <hip/hip_runtime.h>

#define N_NODES 40000
#define N_EDGES 640000
#define IN_DIM 128
#define HID_DIM 256
#define OUT_DIM 256
#define N_CLASSES 10
#define N_GRAPHS 128
#define NEG_SLOPE 0.01f

#define SCAN_BLOCKS ((N_NODES + 255) / 256)  // 157

typedef short bf16x8 __attribute__((ext_vector_type(8)));
typedef float f32x4 __attribute__((ext_vector_type(4)));

// ---- split-bf16 helpers (RNE) ----
__device__ inline unsigned short f2bf(float x) {
  unsigned u = __float_as_uint(x);
  u += 0x7fffu + ((u >> 16) & 1u);
  return (unsigned short)(u >> 16);
}
__device__ inline float bf2f(unsigned short h) {
  return __uint_as_float(((unsigned)h) << 16);
}
__device__ inline unsigned pack_split(float v) {
  unsigned short hi = f2bf(v);
  float r = v - bf2f(hi);
  unsigned short lo = f2bf(r);
  return (unsigned)hi | ((unsigned)lo << 16);
}

// ---------------- edge histogram (both directions) ----------------
__global__ __launch_bounds__(256) void hist_kernel(const int* __restrict__ src,
                                                   const int* __restrict__ dst,
                                                   int* __restrict__ cntOut,
                                                   int* __restrict__ cntIn, int nEdges) {
  int i = blockIdx.x * 256 + threadIdx.x;
  if (i < nEdges) {
    atomicAdd(&cntOut[src[i]], 1);
    atomicAdd(&cntIn[dst[i]], 1);
  }
}

// ---------------- stage 1: per-block exclusive scan + block sums ----------------
__global__ __launch_bounds__(256) void scan1_kernel(const int* __restrict__ cnt,
                                                    int* __restrict__ rowptr,
                                                    int* __restrict__ blockSums) {
  __shared__ int sm[256];
  int i = blockIdx.x * 256 + threadIdx.x;
  int v = (i < N_NODES) ? cnt[i] : 0;
  sm[threadIdx.x] = v;
  __syncthreads();
  for (int off = 1; off < 256; off <<= 1) {
    int t = (threadIdx.x >= off) ? sm[threadIdx.x - off] : 0;
    __syncthreads();
    sm[threadIdx.x] += t;
    __syncthreads();
  }
  if (i < N_NODES) rowptr[i] = sm[threadIdx.x] - v;  // exclusive within block
  if (threadIdx.x == 255) blockSums[blockIdx.x] = sm[255];
}

// ---------------- stage 2: scan block sums (157 values) ----------------
__global__ __launch_bounds__(256) void scan2_kernel(const int* __restrict__ blockSums,
                                                    int* __restrict__ blockOff,
                                                    int* __restrict__ rowptr) {
  __shared__ int sm[256];
  int tid = threadIdx.x;
  int v = (tid < SCAN_BLOCKS) ? blockSums[tid] : 0;
  sm[tid] = v;
  __syncthreads();
  for (int off = 1; off < 256; off <<= 1) {
    int t = (tid >= off) ? sm[tid - off] : 0;
    __syncthreads();
    sm[tid] += t;
    __syncthreads();
  }
  if (tid < SCAN_BLOCKS) blockOff[tid] = sm[tid] - v;  // exclusive
  if (tid == 255) rowptr[N_NODES] = sm[255];           // total edges
}

// ---------------- stage 3: add offsets; init cursor; degree scales; zero pool buffers ----------------
__global__ __launch_bounds__(256) void scan3_kernel(int* __restrict__ rowptr,
                                                    const int* __restrict__ blockOff,
                                                    int* __restrict__ cursor,
                                                    const int* __restrict__ cntIn,
                                                    const int* __restrict__ cntOut,
                                                    float* __restrict__ sIn,
                                                    float* __restrict__ sOut,
                                                    float* __restrict__ poolZero, int nZero) {
  int i = blockIdx.x * 256 + threadIdx.x;
  if (i < N_NODES) {
    int r = rowptr[i] + blockOff[blockIdx.x];
    rowptr[i] = r;
    cursor[i] = r;
    sIn[i] = rsqrtf((float)max(cntIn[i], 1));
    sOut[i] = rsqrtf((float)max(cntOut[i], 1));
  }
  if (i < nZero) poolZero[i] = 0.0f;
}

// ---------------- fill CSR adjacency: eidx[bucket positions] = src ----------------
__global__ __launch_bounds__(256) void fill_kernel(const int* __restrict__ src,
                                                   const int* __restrict__ dst,
                                                   int* __restrict__ cursor,
                                                   int* __restrict__ eidx, int nEdges) {
  int e = blockIdx.x * 256 + threadIdx.x;
  if (e < nEdges) {
    int pos = atomicAdd(&cursor[dst[e]], 1);
    eidx[pos] = src[e];
  }
}

// ---- W split+transpose (both weights, one launch) ----
__global__ __launch_bounds__(256) void wsplit_kernel(const float* __restrict__ W1,
                                                     unsigned* __restrict__ Wt1,
                                                     const float* __restrict__ W2,
                                                     unsigned* __restrict__ Wt2) {
  int i = blockIdx.x * 256 + threadIdx.x;
  constexpr int N1 = IN_DIM * 256;
  if (i < N1) {
    int k = i >> 8;
    int n = i & 255;
    Wt1[(size_t)n * IN_DIM + k] = pack_split(W1[i]);
  } else {
    int j = i - N1;
    if (j < HID_DIM * 256) {
      int k = j >> 8;
      int n = j & 255;
      Wt2[(size_t)n * HID_DIM + k] = pack_split(W2[j]);
    }
  }
}

// ---------------- CSR gather: aggp[v] = split_bf16(s_in[v] * sum h[u]*s_out[u]) ----------------
// 256-thread block = 4 waves = 4 nodes; node idx pinned wave-uniform (s_load path);
// 8-deep edge unroll. BF16 variant reads 2B/elem rows (halves gather traffic).
template <int D, bool BF16>
__global__ __launch_bounds__(256) void gather_kernel(const void* __restrict__ hsrc,
                                                     const float* __restrict__ s_out,
                                                     const float* __restrict__ s_in,
                                                     const int* __restrict__ rowptr,
                                                     const int* __restrict__ eidx,
                                                     unsigned* __restrict__ aggp) {
  constexpr int VEC = D / 64;  // 4 (D=256) or 2 (D=128)
  const int node = __builtin_amdgcn_readfirstlane(blockIdx.x * 4 + (threadIdx.x >> 6));
  const int lane = threadIdx.x & 63;
  const int f0 = lane * VEC;
  const int beg = rowptr[node];
  const int end = rowptr[node + 1];
  float acc[VEC] = {};
  int j = beg;
  for (; j + 7 < end; j += 8) {
    int s[8];
#pragma unroll
    for (int u = 0; u < 8; u++) s[u] = eidx[j + u];
    float v[8][VEC];
#pragma unroll
    for (int u = 0; u < 8; u++) {
      if constexpr (BF16) {
        const unsigned short* row = (const unsigned short*)hsrc + (size_t)s[u] * D + f0;
        if constexpr (VEC == 4) {
          uint2 rv = *reinterpret_cast<const uint2*>(row);
          v[u][0] = bf2f((unsigned short)(rv.x & 0xffffu));
          v[u][1] = bf2f((unsigned short)(rv.x >> 16));
          v[u][2] = bf2f((unsigned short)(rv.y & 0xffffu));
          v[u][3] = bf2f((unsigned short)(rv.y >> 16));
        } else {
          unsigned rv = *reinterpret_cast<const unsigned*>(row);
          v[u][0] = bf2f((unsigned short)(rv & 0xffffu));
          v[u][1] = bf2f((unsigned short)(rv >> 16));
        }
      } else {
        const float* row = (const float*)hsrc + (size_t)s[u] * D + f0;
        if constexpr (VEC == 4) {
          float4 t = *reinterpret_cast<const float4*>(row);
          v[u][0] = t.x; v[u][1] = t.y; v[u][2] = t.z; v[u][3] = t.w;
        } else {
          float2 t = *reinterpret_cast<const float2*>(row);
          v[u][0] = t.x; v[u][1] = t.y;
        }
      }
    }
    float c[8];
#pragma unroll
    for (int u = 0; u < 8; u++) c[u] = s_out[s[u]];
#pragma unroll
    for (int u = 0; u < 8; u++)
#pragma unroll
      for (int q = 0; q < VEC; q++) acc[q] += v[u][q] * c[u];
  }
  for (; j < end; j++) {
    int s = eidx[j];
    float c = s_out[s];
    if constexpr (BF16) {
      const unsigned short* row = (const unsigned short*)hsrc + (size_t)s * D + f0;
#pragma unroll
      for (int q = 0; q < VEC; q++) acc[q] += bf2f(row[q]) * c;
    } else {
      const float* row = (const float*)hsrc + (size_t)s * D + f0;
#pragma unroll
      for (int q = 0; q < VEC; q++) acc[q] += row[q] * c;
    }
  }
  float si = s_in[node];
#pragma unroll
  for (int q = 0; q < VEC; q++) aggp[(size_t)node * D + f0 + q] = pack_split(acc[q] * si);
}

// ---------------- MFMA GEMM: O = lrelu(A @ W + b), split-bf16 3-product ----------------
// Apk: [M][K] packed (hi,lo); Wt: [256][K] packed; O: [M,256] fp32 or bf16.
// 128x128 tile, BK=32, 4 waves (2x2), each wave 64x64 via 4x4 16x16x32 MFMAs x3 products.
template <int K, bool OUT_BF16>
__global__ __launch_bounds__(256) void gemm_mfma_bias_lrelu(const unsigned* __restrict__ Apk,
                                                            const unsigned* __restrict__ Wt,
                                                            const float* __restrict__ bias,
                                                            void* __restrict__ Optr, int M) {
  constexpr int BM = 128, BN = 128, BK = 32;
  constexpr int LDK = BK + 8;  // 40 ushorts/row: frag b128 reads 2-way bank alias (free)
  __shared__ unsigned short Ah[BM][LDK], Al[BM][LDK];
  __shared__ unsigned short Bh[BN][LDK], Bl[BN][LDK];
  const int tid = threadIdx.x;
  const int lane = tid & 63;
  const int wave = tid >> 6;
  const int wr = wave >> 1, wc = wave & 1;  // 2x2 wave grid, 64x64 each
  const int rowBase = blockIdx.x * BM;
  const int colBase = blockIdx.y * BN;
  const int g = lane >> 4;    // 0..3  -> k-group / C row-group
  const int r16 = lane & 15;  // fragment row/col

  f32x4 acc[4][4] = {};

  for (int k0 = 0; k0 < K; k0 += BK) {
    // stage A: 128x32 packed elems, 4 passes x 256 thr x 4 elems (uint4)
#pragma unroll
    for (int p = 0; p < 4; p++) {
      int e = (p * 256 + tid) * 4;
      int r = e >> 5;
      int kc = e & 31;
      int gr = rowBase + r;
      if (gr >= M) gr = M - 1;  // clamp; stores guarded
      uint4 v = *reinterpret_cast<const uint4*>(&Apk[(size_t)gr * K + k0 + kc]);
      *reinterpret_cast<unsigned*>(&Ah[r][kc]) = (v.x & 0xffffu) | (v.y << 16);
      *reinterpret_cast<unsigned*>(&Ah[r][kc + 2]) = (v.z & 0xffffu) | (v.w << 16);
      *reinterpret_cast<unsigned*>(&Al[r][kc]) = (v.x >> 16) | (v.y & 0xffff0000u);
      *reinterpret_cast<unsigned*>(&Al[r][kc + 2]) = (v.z >> 16) | (v.w & 0xffff0000u);
    }
    // stage B: Wt rows are n (K-major), same geometry
#pragma unroll
    for (int p = 0; p < 4; p++) {
      int e = (p * 256 + tid) * 4;
      int n = e >> 5;
      int kc = e & 31;
      uint4 v = *reinterpret_cast<const uint4*>(&Wt[(size_t)(colBase + n) * K + k0 + kc]);
      *reinterpret_cast<unsigned*>(&Bh[n][kc]) = (v.x & 0xffffu) | (v.y << 16);
      *reinterpret_cast<unsigned*>(&Bh[n][kc + 2]) = (v.z & 0xffffu) | (v.w << 16);
      *reinterpret_cast<unsigned*>(&Bl[n][kc]) = (v.x >> 16) | (v.y & 0xffff0000u);
      *reinterpret_cast<unsigned*>(&Bl[n][kc + 2]) = (v.z >> 16) | (v.w & 0xffff0000u);
    }
    __syncthreads();

    // fragments: A[row=lane&15][k=(lane>>4)*8+j], B[k][col=lane&15]
    bf16x8 afh[4], afl[4], bfh[4], bfl[4];
#pragma unroll
    for (int mf = 0; mf < 4; mf++) {
      afh[mf] = *reinterpret_cast<const bf16x8*>(&Ah[wr * 64 + mf * 16 + r16][g * 8]);
      afl[mf] = *reinterpret_cast<const bf16x8*>(&Al[wr * 64 + mf * 16 + r16][g * 8]);
    }
#pragma unroll
    for (int nf = 0; nf < 4; nf++) {
      bfh[nf] = *reinterpret_cast<const bf16x8*>(&Bh[wc * 64 + nf * 16 + r16][g * 8]);
      bfl[nf] = *reinterpret_cast<const bf16x8*>(&Bl[wc * 64 + nf * 16 + r16][g * 8]);
    }
#pragma unroll
    for (int mf = 0; mf < 4; mf++)
#pragma unroll
      for (int nf = 0; nf < 4; nf++) {
        acc[mf][nf] = __builtin_amdgcn_mfma_f32_16x16x32_bf16(afh[mf], bfh[nf], acc[mf][nf], 0, 0, 0);
        acc[mf][nf] = __builtin_amdgcn_mfma_f32_16x16x32_bf16(afh[mf], bfl[nf], acc[mf][nf], 0, 0, 0);
        acc[mf][nf] = __builtin_amdgcn_mfma_f32_16x16x32_bf16(afl[mf], bfh[nf], acc[mf][nf], 0, 0, 0);
      }
    __syncthreads();
  }

  // epilogue: C/D map col=lane&15, row=(lane>>4)*4+reg
#pragma unroll
  for (int mf = 0; mf < 4; mf++)
#pragma unroll
    for (int nf = 0; nf < 4; nf++) {
      int col = colBase + wc * 64 + nf * 16 + r16;
      float bv = bias[col];
#pragma unroll
      for (int j = 0; j < 4; j++) {
        int row = rowBase + wr * 64 + mf * 16 + g * 4 + j;
        if (row < M) {
          float v = acc[mf][nf][j] + bv;
          v = v > 0.0f ? v : NEG_SLOPE * v;
          if constexpr (OUT_BF16) {
            ((unsigned short*)Optr)[(size_t)row * 256 + col] = f2bf(v);
          } else {
            ((float*)Optr)[(size_t)row * 256 + col] = v;
          }
        }
      }
    }
}

// ---------------- per-graph mean pooling (graph_ids sorted) ----------------
// one wave per block; lane reads float4 -> full 1KB row per instruction
__global__ __launch_bounds__(64) void pool_kernel(const float* __restrict__ h,
                                                  const int* __restrict__ gids,
                                                  float* __restrict__ sums,
                                                  float* __restrict__ counts, int nNodes) {
  constexpr int NB = 32;  // nodes per block
  const int lane = threadIdx.x;
  const int n0 = blockIdx.x * NB;
  float4 acc = {0.0f, 0.0f, 0.0f, 0.0f};
  int cur = -1;
  int cnt = 0;
  for (int i = 0; i < NB; i++) {
    int n = n0 + i;
    if (n >= nNodes) break;
    int g = gids[n];
    if (g != cur) {
      if (cur >= 0) {
        float* sp = &sums[(size_t)cur * 256 + lane * 4];
        atomicAdd(sp + 0, acc.x);
        atomicAdd(sp + 1, acc.y);
        atomicAdd(sp + 2, acc.z);
        atomicAdd(sp + 3, acc.w);
        if (lane == 0) atomicAdd(&counts[cur], (float)cnt);
      }
      cur = g;
      acc = {0.0f, 0.0f, 0.0f, 0.0f};
      cnt = 0;
    }
    float4 v = *reinterpret_cast<const float4*>(&h[(size_t)n * 256 + lane * 4]);
    acc.x += v.x;
    acc.y += v.y;
    acc.z += v.z;
    acc.w += v.w;
    cnt++;
  }
  if (cur >= 0) {
    float* sp = &sums[(size_t)cur * 256 + lane * 4];
    atomicAdd(sp + 0, acc.x);
    atomicAdd(sp + 1, acc.y);
    atomicAdd(sp + 2, acc.z);
    atomicAdd(sp + 3, acc.w);
    if (lane == 0) atomicAdd(&counts[cur], (float)cnt);
  }
}

// ---------------- classifier: out = (sums/count) @ Wc + bc ----------------
__global__ __launch_bounds__(256) void cls_kernel(const float* __restrict__ sums,
                                                  const float* __restrict__ counts,
                                                  const float* __restrict__ Wc,
                                                  const float* __restrict__ bc,
                                                  float* __restrict__ out) {
  __shared__ float hg[256];
  int g = blockIdx.x;
  float invc = 1.0f / fmaxf(counts[g], 1.0f);
  hg[threadIdx.x] = sums[(size_t)g * 256 + threadIdx.x] * invc;
  __syncthreads();
  if (threadIdx.x < N_CLASSES) {
    float a = bc[threadIdx.x];
    for (int k = 0; k < 256; k++) a += hg[k] * Wc[k * N_CLASSES + threadIdx.x];
    out[g * N_CLASSES + threadIdx.x] = a;
  }
}

static constexpr size_t align1k(size_t x) { return (x + 1023) & ~(size_t)1023; }

extern "C" void kernel_launch(void* const* d_in, const int* in_sizes, int n_in,
                              void* d_out, int out_size, void* d_ws, size_t ws_size,
                              hipStream_t stream) {
  const float* x = (const float*)d_in[0];
  const int* src = (const int*)d_in[1];
  const int* dst = (const int*)d_in[2];
  const int* gids = (const int*)d_in[3];
  const float* W1 = (const float*)d_in[4];
  const float* b1 = (const float*)d_in[5];
  const float* W2 = (const float*)d_in[6];
  const float* b2 = (const float*)d_in[7];
  const float* Wc = (const float*)d_in[8];
  const float* bc = (const float*)d_in[9];
  float* out = (float*)d_out;

  // ---------------- workspace layout ----------------
  char* ws = (char*)d_ws;
  constexpr size_t OFF_CNT_IN = 0;                                      // 40000 ints
  constexpr size_t OFF_CNT_OUT = OFF_CNT_IN + (size_t)N_NODES * 4;      // 40000 ints
  constexpr size_t OFF_ROWPTR = align1k(OFF_CNT_OUT + (size_t)N_NODES * 4);  // 40001 ints
  constexpr size_t OFF_CURSOR = align1k(OFF_ROWPTR + (size_t)(N_NODES + 1) * 4);
  constexpr size_t OFF_BSUM = align1k(OFF_CURSOR + (size_t)N_NODES * 4);  // 157 ints
  constexpr size_t OFF_BOFF = align1k(OFF_BSUM + 1024);                   // 157 ints
  constexpr size_t OFF_SIN = align1k(OFF_BOFF + 1024);
  constexpr size_t OFF_SOUT = OFF_SIN + (size_t)N_NODES * 4;
  constexpr size_t OFF_PCNT = align1k(OFF_SOUT + (size_t)N_NODES * 4);  // 128 floats
  constexpr size_t OFF_SUMS = align1k(OFF_PCNT + 512);                  // 128*256 floats
  constexpr size_t OFF_EIDX = align1k(OFF_SUMS + (size_t)N_GRAPHS * 256 * 4);
  constexpr size_t OFF_AGG = align1k(OFF_EIDX + (size_t)N_EDGES * 4);
  constexpr size_t SZ_BIG = (size_t)N_NODES * 256 * 4;  // 40,960,000
  constexpr size_t OFF_H = align1k(OFF_AGG + SZ_BIG);   // h1 (bf16, 20MB) then h2 (fp32, 40MB)
  constexpr size_t OFF_WT1 = align1k(OFF_H + SZ_BIG);                   // 256x128 uint
  constexpr size_t OFF_WT2 = align1k(OFF_WT1 + 256 * 128 * 4);          // 256x256 uint

  int* cntIn = (int*)(ws + OFF_CNT_IN);
  int* cntOut = (int*)(ws + OFF_CNT_OUT);
  int* rowptr = (int*)(ws + OFF_ROWPTR);
  int* cursor = (int*)(ws + OFF_CURSOR);
  int* bsum = (int*)(ws + OFF_BSUM);
  int* boff = (int*)(ws + OFF_BOFF);
  float* s_in = (float*)(ws + OFF_SIN);
  float* s_out = (float*)(ws + OFF_SOUT);
  float* counts = (float*)(ws + OFF_PCNT);
  float* sums = (float*)(ws + OFF_SUMS);
  int* eidx = (int*)(ws + OFF_EIDX);
  unsigned* aggp = (unsigned*)(ws + OFF_AGG);
  unsigned short* h1b = (unsigned short*)(ws + OFF_H);  // bf16 layer-1 activations
  float* h2 = (float*)(ws + OFF_H);                     // fp32 layer-2 activations (overwrites h1b)
  unsigned* Wt1 = (unsigned*)(ws + OFF_WT1);
  unsigned* Wt2 = (unsigned*)(ws + OFF_WT2);

  // zero: histogram counters (pool counts+sums zeroed inside scan3)
  hipMemsetAsync(ws + OFF_CNT_IN, 0, 2 * (size_t)N_NODES * 4, stream);

  // number of floats to zero starting at OFF_PCNT (covers counts pad + sums)
  const int nZero = (int)((OFF_SUMS - OFF_PCNT) / 4 + (size_t)N_GRAPHS * 256);

  // ---------------- CSR build + degree scales + W splits ----------------
  hist_kernel<<<(N_EDGES + 255) / 256, 256, 0, stream>>>(src, dst, cntOut, cntIn, N_EDGES);
  scan1_kernel<<<SCAN_BLOCKS, 256, 0, stream>>>(cntIn, rowptr, bsum);
  scan2_kernel<<<1, 256, 0, stream>>>(bsum, boff, rowptr);
  scan3_kernel<<<SCAN_BLOCKS, 256, 0, stream>>>(rowptr, boff, cursor, cntIn, cntOut, s_in, s_out,
                                                counts, nZero);
  fill_kernel<<<(N_EDGES + 255) / 256, 256, 0, stream>>>(src, dst, cursor, eidx, N_EDGES);
  wsplit_kernel<<<((IN_DIM + HID_DIM) * 256 + 255) / 256, 256, 0, stream>>>(W1, Wt1, W2, Wt2);

  dim3 ggrid((N_NODES + 127) / 128, 2);

  // ---------------- layer 1 (h1 stored bf16) ----------------
  gather_kernel<IN_DIM, false><<<N_NODES / 4, 256, 0, stream>>>(x, s_out, s_in, rowptr, eidx, aggp);
  gemm_mfma_bias_lrelu<IN_DIM, true><<<ggrid, 256, 0, stream>>>(aggp, Wt1, b1, h1b, N_NODES);

  // ---------------- layer 2 (gather from bf16 h1; h2 fp32) ----------------
  gather_kernel<HID_DIM, true><<<N_NODES / 4, 256, 0, stream>>>(h1b, s_out, s_in, rowptr, eidx, aggp);
  gemm_mfma_bias_lrelu<HID_DIM, false><<<ggrid, 256, 0, stream>>>(aggp, Wt2, b2, h2, N_NODES);

  // ---------------- pooling + classifier ----------------
  pool_kernel<<<(N_NODES + 31) / 32, 64, 0, stream>>>(h2, gids, sums, counts, N_NODES);
  cls_kernel<<<N_GRAPHS, 256, 0, stream>>>(sums, counts, Wc, bc, out);
}

// Round 11
// 340.560 us; speedup vs baseline: 1.6193x; 1.0612x over previous
//
#include <hip/hip_runtime.h>

#define N_NODES 40000
#define N_EDGES 640000
#define IN_DIM 128
#define HID_DIM 256
#define OUT_DIM 256
#define N_CLASSES 10
#define N_GRAPHS 128
#define NEG_SLOPE 0.01f

#define SCAN_BLOCKS ((N_NODES + 255) / 256)  // 157
#define NSLICE 16                            // edge slices per direction for LDS hist

typedef short bf16x8 __attribute__((ext_vector_type(8)));
typedef float f32x4 __attribute__((ext_vector_type(4)));

// ---- numeric helpers ----
__device__ inline unsigned short f2bf(float x) {
  unsigned u = __float_as_uint(x);
  u += 0x7fffu + ((u >> 16) & 1u);
  return (unsigned short)(u >> 16);
}
__device__ inline float bf2f(unsigned short h) {
  return __uint_as_float(((unsigned)h) << 16);
}
__device__ inline unsigned pack_split(float v) {
  unsigned short hi = f2bf(v);
  float r = v - bf2f(hi);
  unsigned short lo = f2bf(r);
  return (unsigned)hi | ((unsigned)lo << 16);
}
__device__ inline float h2f(unsigned short u) {
  _Float16 h;
  __builtin_memcpy(&h, &u, 2);
  return (float)h;
}
__device__ inline unsigned short f2h(float x) {
  _Float16 h = (_Float16)x;
  unsigned short u;
  __builtin_memcpy(&u, &h, 2);
  return u;
}

// ---------------- LDS-privatized degree histogram (no global atomics) ----------------
// grid (NSLICE, 2): y=0 counts dst keys (in-degree), y=1 counts src keys (out-degree).
// Each block: full 40000-bin LDS histogram over its edge slice -> coalesced partial store.
__global__ __launch_bounds__(256) void hist_lds_kernel(const int* __restrict__ dst,
                                                       const int* __restrict__ src,
                                                       int* __restrict__ partials) {
  __shared__ int hbin[N_NODES];  // 160000 B (gfx950 WG limit 160 KiB)
  const int slice = blockIdx.x;
  const int dir = blockIdx.y;
  const int* keys = dir ? src : dst;
  for (int i = threadIdx.x; i < N_NODES; i += 256) hbin[i] = 0;
  __syncthreads();
  constexpr int PER = N_EDGES / NSLICE;  // 40000
  const int e0 = slice * PER;
  for (int e = e0 + threadIdx.x; e < e0 + PER; e += 256) atomicAdd(&hbin[keys[e]], 1);
  __syncthreads();
  int* out = partials + ((size_t)dir * NSLICE + slice) * N_NODES;
  for (int i = threadIdx.x; i < N_NODES; i += 256) out[i] = hbin[i];
}

// ---------------- x -> fp16 conversion ----------------
__global__ __launch_bounds__(256) void xhalf_kernel(const float* __restrict__ x,
                                                    unsigned short* __restrict__ xh) {
  int base = (blockIdx.x * 256 + threadIdx.x) * 8;
  if (base < N_NODES * IN_DIM) {
    float4 a = *reinterpret_cast<const float4*>(&x[base]);
    float4 b = *reinterpret_cast<const float4*>(&x[base + 4]);
    unsigned short o[8];
    const float* pa = &a.x;
    const float* pb = &b.x;
#pragma unroll
    for (int q = 0; q < 4; q++) o[q] = f2h(pa[q]);
#pragma unroll
    for (int q = 0; q < 4; q++) o[4 + q] = f2h(pb[q]);
    *reinterpret_cast<uint4*>(&xh[base]) = *reinterpret_cast<const uint4*>(o);
  }
}

// ---------------- stage 1: sum in-degree partials; per-block exclusive scan ----------------
__global__ __launch_bounds__(256) void scan1_kernel(const int* __restrict__ partials,
                                                    int* __restrict__ cntIn,
                                                    int* __restrict__ rowptr,
                                                    int* __restrict__ blockSums) {
  __shared__ int sm[256];
  int i = blockIdx.x * 256 + threadIdx.x;
  int v = 0;
  if (i < N_NODES) {
#pragma unroll
    for (int s = 0; s < NSLICE; s++) v += partials[(size_t)s * N_NODES + i];
    cntIn[i] = v;
  }
  sm[threadIdx.x] = v;
  __syncthreads();
  for (int off = 1; off < 256; off <<= 1) {
    int t = (threadIdx.x >= off) ? sm[threadIdx.x - off] : 0;
    __syncthreads();
    sm[threadIdx.x] += t;
    __syncthreads();
  }
  if (i < N_NODES) rowptr[i] = sm[threadIdx.x] - v;  // exclusive within block
  if (threadIdx.x == 255) blockSums[blockIdx.x] = sm[255];
}

// ---------------- stage 2: scan block sums (157 values) ----------------
__global__ __launch_bounds__(256) void scan2_kernel(const int* __restrict__ blockSums,
                                                    int* __restrict__ blockOff,
                                                    int* __restrict__ rowptr) {
  __shared__ int sm[256];
  int tid = threadIdx.x;
  int v = (tid < SCAN_BLOCKS) ? blockSums[tid] : 0;
  sm[tid] = v;
  __syncthreads();
  for (int off = 1; off < 256; off <<= 1) {
    int t = (tid >= off) ? sm[tid - off] : 0;
    __syncthreads();
    sm[tid] += t;
    __syncthreads();
  }
  if (tid < SCAN_BLOCKS) blockOff[tid] = sm[tid] - v;  // exclusive
  if (tid == 255) rowptr[N_NODES] = sm[255];           // total edges
}

// ---------------- stage 3: offsets; cursor; degree scales (sum out partials); zero pool ----------------
__global__ __launch_bounds__(256) void scan3_kernel(int* __restrict__ rowptr,
                                                    const int* __restrict__ blockOff,
                                                    int* __restrict__ cursor,
                                                    const int* __restrict__ cntIn,
                                                    const int* __restrict__ part1,
                                                    float* __restrict__ sIn,
                                                    float* __restrict__ sOut,
                                                    float* __restrict__ poolZero, int nZero) {
  int i = blockIdx.x * 256 + threadIdx.x;
  if (i < N_NODES) {
    int r = rowptr[i] + blockOff[blockIdx.x];
    rowptr[i] = r;
    cursor[i] = r;
    sIn[i] = rsqrtf((float)max(cntIn[i], 1));
    int co = 0;
#pragma unroll
    for (int s = 0; s < NSLICE; s++) co += part1[(size_t)s * N_NODES + i];
    sOut[i] = rsqrtf((float)max(co, 1));
  }
  if (i < nZero) poolZero[i] = 0.0f;
}

// ---------------- fill CSR adjacency: eidx[bucket positions] = src ----------------
__global__ __launch_bounds__(256) void fill_kernel(const int* __restrict__ src,
                                                   const int* __restrict__ dst,
                                                   int* __restrict__ cursor,
                                                   int* __restrict__ eidx, int nEdges) {
  int e = blockIdx.x * 256 + threadIdx.x;
  if (e < nEdges) {
    int pos = atomicAdd(&cursor[dst[e]], 1);
    eidx[pos] = src[e];
  }
}

// ---- W split+transpose (both weights, one launch) ----
__global__ __launch_bounds__(256) void wsplit_kernel(const float* __restrict__ W1,
                                                     unsigned* __restrict__ Wt1,
                                                     const float* __restrict__ W2,
                                                     unsigned* __restrict__ Wt2) {
  int i = blockIdx.x * 256 + threadIdx.x;
  constexpr int N1 = IN_DIM * 256;
  if (i < N1) {
    int k = i >> 8;
    int n = i & 255;
    Wt1[(size_t)n * IN_DIM + k] = pack_split(W1[i]);
  } else {
    int j = i - N1;
    if (j < HID_DIM * 256) {
      int k = j >> 8;
      int n = j & 255;
      Wt2[(size_t)n * HID_DIM + k] = pack_split(W2[j]);
    }
  }
}

// ---------------- CSR gather: aggp[v] = split_bf16(s_in[v] * sum h[u]*s_out[u]) ----------------
// 4 waves/block = 4 nodes; node idx wave-uniform (s_load path); 8-deep edge unroll.
// MODE: 0 = fp32 rows, 1 = bf16 rows, 2 = fp16 rows.
template <int D, int MODE>
__global__ __launch_bounds__(256) void gather_kernel(const void* __restrict__ hsrc,
                                                     const float* __restrict__ s_out,
                                                     const float* __restrict__ s_in,
                                                     const int* __restrict__ rowptr,
                                                     const int* __restrict__ eidx,
                                                     unsigned* __restrict__ aggp) {
  constexpr int VEC = D / 64;  // 4 (D=256) or 2 (D=128)
  const int node = __builtin_amdgcn_readfirstlane(blockIdx.x * 4 + (threadIdx.x >> 6));
  const int lane = threadIdx.x & 63;
  const int f0 = lane * VEC;
  const int beg = rowptr[node];
  const int end = rowptr[node + 1];
  float acc[VEC] = {};
  int j = beg;
  for (; j + 7 < end; j += 8) {
    int s[8];
#pragma unroll
    for (int u = 0; u < 8; u++) s[u] = eidx[j + u];
    float v[8][VEC];
#pragma unroll
    for (int u = 0; u < 8; u++) {
      if constexpr (MODE == 0) {
        const float* row = (const float*)hsrc + (size_t)s[u] * D + f0;
        if constexpr (VEC == 4) {
          float4 t = *reinterpret_cast<const float4*>(row);
          v[u][0] = t.x; v[u][1] = t.y; v[u][2] = t.z; v[u][3] = t.w;
        } else {
          float2 t = *reinterpret_cast<const float2*>(row);
          v[u][0] = t.x; v[u][1] = t.y;
        }
      } else {
        const unsigned short* row = (const unsigned short*)hsrc + (size_t)s[u] * D + f0;
        if constexpr (VEC == 4) {
          uint2 rv = *reinterpret_cast<const uint2*>(row);
          unsigned short w[4] = {(unsigned short)(rv.x & 0xffffu), (unsigned short)(rv.x >> 16),
                                 (unsigned short)(rv.y & 0xffffu), (unsigned short)(rv.y >> 16)};
#pragma unroll
          for (int q = 0; q < 4; q++) v[u][q] = (MODE == 1) ? bf2f(w[q]) : h2f(w[q]);
        } else {
          unsigned rv = *reinterpret_cast<const unsigned*>(row);
          unsigned short w[2] = {(unsigned short)(rv & 0xffffu), (unsigned short)(rv >> 16)};
#pragma unroll
          for (int q = 0; q < 2; q++) v[u][q] = (MODE == 1) ? bf2f(w[q]) : h2f(w[q]);
        }
      }
    }
    float c[8];
#pragma unroll
    for (int u = 0; u < 8; u++) c[u] = s_out[s[u]];
#pragma unroll
    for (int u = 0; u < 8; u++)
#pragma unroll
      for (int q = 0; q < VEC; q++) acc[q] += v[u][q] * c[u];
  }
  for (; j < end; j++) {
    int s = eidx[j];
    float c = s_out[s];
    if constexpr (MODE == 0) {
      const float* row = (const float*)hsrc + (size_t)s * D + f0;
#pragma unroll
      for (int q = 0; q < VEC; q++) acc[q] += row[q] * c;
    } else {
      const unsigned short* row = (const unsigned short*)hsrc + (size_t)s * D + f0;
#pragma unroll
      for (int q = 0; q < VEC; q++)
        acc[q] += ((MODE == 1) ? bf2f(row[q]) : h2f(row[q])) * c;
    }
  }
  float si = s_in[node];
#pragma unroll
  for (int q = 0; q < VEC; q++) aggp[(size_t)node * D + f0 + q] = pack_split(acc[q] * si);
}

// ---------------- MFMA GEMM: O = lrelu(A @ W + b), split-bf16 3-product ----------------
template <int K, bool OUT_BF16>
__global__ __launch_bounds__(256) void gemm_mfma_bias_lrelu(const unsigned* __restrict__ Apk,
                                                            const unsigned* __restrict__ Wt,
                                                            const float* __restrict__ bias,
                                                            void* __restrict__ Optr, int M) {
  constexpr int BM = 128, BN = 128, BK = 32;
  constexpr int LDK = BK + 8;  // 40 ushorts/row: frag b128 reads 2-way bank alias (free)
  __shared__ unsigned short Ah[BM][LDK], Al[BM][LDK];
  __shared__ unsigned short Bh[BN][LDK], Bl[BN][LDK];
  const int tid = threadIdx.x;
  const int lane = tid & 63;
  const int wave = tid >> 6;
  const int wr = wave >> 1, wc = wave & 1;  // 2x2 wave grid, 64x64 each
  const int rowBase = blockIdx.x * BM;
  const int colBase = blockIdx.y * BN;
  const int g = lane >> 4;    // 0..3  -> k-group / C row-group
  const int r16 = lane & 15;  // fragment row/col

  f32x4 acc[4][4] = {};

  for (int k0 = 0; k0 < K; k0 += BK) {
#pragma unroll
    for (int p = 0; p < 4; p++) {
      int e = (p * 256 + tid) * 4;
      int r = e >> 5;
      int kc = e & 31;
      int gr = rowBase + r;
      if (gr >= M) gr = M - 1;  // clamp; stores guarded
      uint4 v = *reinterpret_cast<const uint4*>(&Apk[(size_t)gr * K + k0 + kc]);
      *reinterpret_cast<unsigned*>(&Ah[r][kc]) = (v.x & 0xffffu) | (v.y << 16);
      *reinterpret_cast<unsigned*>(&Ah[r][kc + 2]) = (v.z & 0xffffu) | (v.w << 16);
      *reinterpret_cast<unsigned*>(&Al[r][kc]) = (v.x >> 16) | (v.y & 0xffff0000u);
      *reinterpret_cast<unsigned*>(&Al[r][kc + 2]) = (v.z >> 16) | (v.w & 0xffff0000u);
    }
#pragma unroll
    for (int p = 0; p < 4; p++) {
      int e = (p * 256 + tid) * 4;
      int n = e >> 5;
      int kc = e & 31;
      uint4 v = *reinterpret_cast<const uint4*>(&Wt[(size_t)(colBase + n) * K + k0 + kc]);
      *reinterpret_cast<unsigned*>(&Bh[n][kc]) = (v.x & 0xffffu) | (v.y << 16);
      *reinterpret_cast<unsigned*>(&Bh[n][kc + 2]) = (v.z & 0xffffu) | (v.w << 16);
      *reinterpret_cast<unsigned*>(&Bl[n][kc]) = (v.x >> 16) | (v.y & 0xffff0000u);
      *reinterpret_cast<unsigned*>(&Bl[n][kc + 2]) = (v.z >> 16) | (v.w & 0xffff0000u);
    }
    __syncthreads();

    bf16x8 afh[4], afl[4], bfh[4], bfl[4];
#pragma unroll
    for (int mf = 0; mf < 4; mf++) {
      afh[mf] = *reinterpret_cast<const bf16x8*>(&Ah[wr * 64 + mf * 16 + r16][g * 8]);
      afl[mf] = *reinterpret_cast<const bf16x8*>(&Al[wr * 64 + mf * 16 + r16][g * 8]);
    }
#pragma unroll
    for (int nf = 0; nf < 4; nf++) {
      bfh[nf] = *reinterpret_cast<const bf16x8*>(&Bh[wc * 64 + nf * 16 + r16][g * 8]);
      bfl[nf] = *reinterpret_cast<const bf16x8*>(&Bl[wc * 64 + nf * 16 + r16][g * 8]);
    }
#pragma unroll
    for (int mf = 0; mf < 4; mf++)
#pragma unroll
      for (int nf = 0; nf < 4; nf++) {
        acc[mf][nf] = __builtin_amdgcn_mfma_f32_16x16x32_bf16(afh[mf], bfh[nf], acc[mf][nf], 0, 0, 0);
        acc[mf][nf] = __builtin_amdgcn_mfma_f32_16x16x32_bf16(afh[mf], bfl[nf], acc[mf][nf], 0, 0, 0);
        acc[mf][nf] = __builtin_amdgcn_mfma_f32_16x16x32_bf16(afl[mf], bfh[nf], acc[mf][nf], 0, 0, 0);
      }
    __syncthreads();
  }

#pragma unroll
  for (int mf = 0; mf < 4; mf++)
#pragma unroll
    for (int nf = 0; nf < 4; nf++) {
      int col = colBase + wc * 64 + nf * 16 + r16;
      float bv = bias[col];
#pragma unroll
      for (int j = 0; j < 4; j++) {
        int row = rowBase + wr * 64 + mf * 16 + g * 4 + j;
        if (row < M) {
          float v = acc[mf][nf][j] + bv;
          v = v > 0.0f ? v : NEG_SLOPE * v;
          if constexpr (OUT_BF16) {
            ((unsigned short*)Optr)[(size_t)row * 256 + col] = f2bf(v);
          } else {
            ((float*)Optr)[(size_t)row * 256 + col] = v;
          }
        }
      }
    }
}

// ---------------- per-graph mean pooling (graph_ids sorted) ----------------
__global__ __launch_bounds__(64) void pool_kernel(const float* __restrict__ h,
                                                  const int* __restrict__ gids,
                                                  float* __restrict__ sums,
                                                  float* __restrict__ counts, int nNodes) {
  constexpr int NB = 32;  // nodes per block
  const int lane = threadIdx.x;
  const int n0 = blockIdx.x * NB;
  float4 acc = {0.0f, 0.0f, 0.0f, 0.0f};
  int cur = -1;
  int cnt = 0;
  for (int i = 0; i < NB; i++) {
    int n = n0 + i;
    if (n >= nNodes) break;
    int g = gids[n];
    if (g != cur) {
      if (cur >= 0) {
        float* sp = &sums[(size_t)cur * 256 + lane * 4];
        atomicAdd(sp + 0, acc.x);
        atomicAdd(sp + 1, acc.y);
        atomicAdd(sp + 2, acc.z);
        atomicAdd(sp + 3, acc.w);
        if (lane == 0) atomicAdd(&counts[cur], (float)cnt);
      }
      cur = g;
      acc = {0.0f, 0.0f, 0.0f, 0.0f};
      cnt = 0;
    }
    float4 v = *reinterpret_cast<const float4*>(&h[(size_t)n * 256 + lane * 4]);
    acc.x += v.x;
    acc.y += v.y;
    acc.z += v.z;
    acc.w += v.w;
    cnt++;
  }
  if (cur >= 0) {
    float* sp = &sums[(size_t)cur * 256 + lane * 4];
    atomicAdd(sp + 0, acc.x);
    atomicAdd(sp + 1, acc.y);
    atomicAdd(sp + 2, acc.z);
    atomicAdd(sp + 3, acc.w);
    if (lane == 0) atomicAdd(&counts[cur], (float)cnt);
  }
}

// ---------------- classifier: out = (sums/count) @ Wc + bc ----------------
__global__ __launch_bounds__(256) void cls_kernel(const float* __restrict__ sums,
                                                  const float* __restrict__ counts,
                                                  const float* __restrict__ Wc,
                                                  const float* __restrict__ bc,
                                                  float* __restrict__ out) {
  __shared__ float hg[256];
  int g = blockIdx.x;
  float invc = 1.0f / fmaxf(counts[g], 1.0f);
  hg[threadIdx.x] = sums[(size_t)g * 256 + threadIdx.x] * invc;
  __syncthreads();
  if (threadIdx.x < N_CLASSES) {
    float a = bc[threadIdx.x];
    for (int k = 0; k < 256; k++) a += hg[k] * Wc[k * N_CLASSES + threadIdx.x];
    out[g * N_CLASSES + threadIdx.x] = a;
  }
}

static constexpr size_t align1k(size_t x) { return (x + 1023) & ~(size_t)1023; }

extern "C" void kernel_launch(void* const* d_in, const int* in_sizes, int n_in,
                              void* d_out, int out_size, void* d_ws, size_t ws_size,
                              hipStream_t stream) {
  const float* x = (const float*)d_in[0];
  const int* src = (const int*)d_in[1];
  const int* dst = (const int*)d_in[2];
  const int* gids = (const int*)d_in[3];
  const float* W1 = (const float*)d_in[4];
  const float* b1 = (const float*)d_in[5];
  const float* W2 = (const float*)d_in[6];
  const float* b2 = (const float*)d_in[7];
  const float* Wc = (const float*)d_in[8];
  const float* bc = (const float*)d_in[9];
  float* out = (float*)d_out;

  // ---------------- workspace layout ----------------
  char* ws = (char*)d_ws;
  constexpr size_t OFF_CNT_IN = 0;  // 40000 ints (summed in-degree, written by scan1)
  constexpr size_t OFF_ROWPTR = align1k(OFF_CNT_IN + (size_t)N_NODES * 4);
  constexpr size_t OFF_CURSOR = align1k(OFF_ROWPTR + (size_t)(N_NODES + 1) * 4);
  constexpr size_t OFF_BSUM = align1k(OFF_CURSOR + (size_t)N_NODES * 4);
  constexpr size_t OFF_BOFF = align1k(OFF_BSUM + 1024);
  constexpr size_t OFF_SIN = align1k(OFF_BOFF + 1024);
  constexpr size_t OFF_SOUT = OFF_SIN + (size_t)N_NODES * 4;
  constexpr size_t OFF_PCNT = align1k(OFF_SOUT + (size_t)N_NODES * 4);  // 128 floats
  constexpr size_t OFF_SUMS = align1k(OFF_PCNT + 512);                  // 128*256 floats
  constexpr size_t OFF_EIDX = align1k(OFF_SUMS + (size_t)N_GRAPHS * 256 * 4);
  constexpr size_t OFF_AGG = align1k(OFF_EIDX + (size_t)N_EDGES * 4);
  constexpr size_t SZ_BIG = (size_t)N_NODES * 256 * 4;  // 40,960,000
  constexpr size_t OFF_H = align1k(OFF_AGG + SZ_BIG);   // h1 (bf16) then h2 (fp32)
  constexpr size_t OFF_WT1 = align1k(OFF_H + SZ_BIG);
  constexpr size_t OFF_WT2 = align1k(OFF_WT1 + 256 * 128 * 4);
  constexpr size_t OFF_PART = align1k(OFF_WT2 + 256 * 256 * 4);  // 2*NSLICE*40000 ints
  constexpr size_t OFF_XH = align1k(OFF_PART + (size_t)2 * NSLICE * N_NODES * 4);  // fp16 x

  int* cntIn = (int*)(ws + OFF_CNT_IN);
  int* rowptr = (int*)(ws + OFF_ROWPTR);
  int* cursor = (int*)(ws + OFF_CURSOR);
  int* bsum = (int*)(ws + OFF_BSUM);
  int* boff = (int*)(ws + OFF_BOFF);
  float* s_in = (float*)(ws + OFF_SIN);
  float* s_out = (float*)(ws + OFF_SOUT);
  float* counts = (float*)(ws + OFF_PCNT);
  float* sums = (float*)(ws + OFF_SUMS);
  int* eidx = (int*)(ws + OFF_EIDX);
  unsigned* aggp = (unsigned*)(ws + OFF_AGG);
  unsigned short* h1b = (unsigned short*)(ws + OFF_H);  // bf16 layer-1 activations
  float* h2 = (float*)(ws + OFF_H);                     // fp32 layer-2 activations
  unsigned* Wt1 = (unsigned*)(ws + OFF_WT1);
  unsigned* Wt2 = (unsigned*)(ws + OFF_WT2);
  int* partials = (int*)(ws + OFF_PART);
  unsigned short* xh = (unsigned short*)(ws + OFF_XH);

  // floats to zero starting at OFF_PCNT (counts pad + sums) — done inside scan3
  const int nZero = (int)((OFF_SUMS - OFF_PCNT) / 4 + (size_t)N_GRAPHS * 256);

  // ---------------- CSR build + degree scales + conversions ----------------
  hist_lds_kernel<<<dim3(NSLICE, 2), 256, 0, stream>>>(dst, src, partials);
  xhalf_kernel<<<(N_NODES * IN_DIM / 8 + 255) / 256, 256, 0, stream>>>(x, xh);
  wsplit_kernel<<<((IN_DIM + HID_DIM) * 256 + 255) / 256, 256, 0, stream>>>(W1, Wt1, W2, Wt2);
  scan1_kernel<<<SCAN_BLOCKS, 256, 0, stream>>>(partials, cntIn, rowptr, bsum);
  scan2_kernel<<<1, 256, 0, stream>>>(bsum, boff, rowptr);
  scan3_kernel<<<SCAN_BLOCKS, 256, 0, stream>>>(rowptr, boff, cursor, cntIn,
                                                partials + (size_t)NSLICE * N_NODES, s_in, s_out,
                                                counts, nZero);
  fill_kernel<<<(N_EDGES + 255) / 256, 256, 0, stream>>>(src, dst, cursor, eidx, N_EDGES);

  dim3 ggrid((N_NODES + 127) / 128, 2);

  // ---------------- layer 1 (gather fp16 x; h1 stored bf16) ----------------
  gather_kernel<IN_DIM, 2><<<N_NODES / 4, 256, 0, stream>>>(xh, s_out, s_in, rowptr, eidx, aggp);
  gemm_mfma_bias_lrelu<IN_DIM, true><<<ggrid, 256, 0, stream>>>(aggp, Wt1, b1, h1b, N_NODES);

  // ---------------- layer 2 (gather bf16 h1; h2 fp32) ----------------
  gather_kernel<HID_DIM, 1><<<N_NODES / 4, 256, 0, stream>>>(h1b, s_out, s_in, rowptr, eidx, aggp);
  gemm_mfma_bias_lrelu<HID_DIM, false><<<ggrid, 256, 0, stream>>>(aggp, Wt2, b2, h2, N_NODES);

  // ---------------- pooling + classifier ----------------
  pool_kernel<<<(N_NODES + 31) / 32, 64, 0, stream>>>(h2, gids, sums, counts, N_NODES);
  cls_kernel<<<N_GRAPHS, 256, 0, stream>>>(sums, counts, Wc, bc, out);
}

// Round 13
// 335.249 us; speedup vs baseline: 1.6449x; 1.0158x over previous
//
#include <hip/hip_runtime.h>

#define N_NODES 40000
#define N_EDGES 640000
#define IN_DIM 128
#define HID_DIM 256
#define OUT_DIM 256
#define N_CLASSES 10
#define N_GRAPHS 128
#define NEG_SLOPE 0.01f
#define CAP 64  // padded-CSR slots per node; in-deg ~ Poisson(16), P(>=64) ~ 3e-22

#define DS_BLOCKS ((N_NODES + 255) / 256)  // 157

typedef short bf16x8 __attribute__((ext_vector_type(8)));
typedef float f32x4 __attribute__((ext_vector_type(4)));

// ---- numeric helpers ----
__device__ inline unsigned short f2bf(float x) {
  unsigned u = __float_as_uint(x);
  u += 0x7fffu + ((u >> 16) & 1u);
  return (unsigned short)(u >> 16);
}
__device__ inline float bf2f(unsigned short h) {
  return __uint_as_float(((unsigned)h) << 16);
}
__device__ inline unsigned pack_split(float v) {
  unsigned short hi = f2bf(v);
  float r = v - bf2f(hi);
  unsigned short lo = f2bf(r);
  return (unsigned)hi | ((unsigned)lo << 16);
}
__device__ inline float h2f(unsigned short u) {
  _Float16 h;
  __builtin_memcpy(&h, &u, 2);
  return (float)h;
}
__device__ inline unsigned short f2h(float x) {
  _Float16 h = (_Float16)x;
  unsigned short u;
  __builtin_memcpy(&u, &h, 2);
  return u;
}

// ---------------- merged hist+fill: padded CSR in one edge pass ----------------
__global__ __launch_bounds__(256) void fill_padded_kernel(const int* __restrict__ src,
                                                          const int* __restrict__ dst,
                                                          int* __restrict__ cntIn,
                                                          int* __restrict__ cntOut,
                                                          unsigned short* __restrict__ eidx,
                                                          int nEdges) {
  int e = blockIdx.x * 256 + threadIdx.x;
  if (e < nEdges) {
    int s = src[e];
    int d = dst[e];
    int pos = atomicAdd(&cntIn[d], 1);
    eidx[(size_t)d * CAP + pos] = (unsigned short)s;
    atomicAdd(&cntOut[s], 1);
  }
}

// ---------------- degree scales + pool-buffer zeroing ----------------
__global__ __launch_bounds__(256) void degscale_kernel(const int* __restrict__ cntIn,
                                                       const int* __restrict__ cntOut,
                                                       float* __restrict__ sIn,
                                                       float* __restrict__ sOut,
                                                       float* __restrict__ poolZero, int nZero) {
  int i = blockIdx.x * 256 + threadIdx.x;
  if (i < N_NODES) {
    sIn[i] = rsqrtf((float)max(cntIn[i], 1));
    sOut[i] = rsqrtf((float)max(cntOut[i], 1));
  }
  if (i < nZero) poolZero[i] = 0.0f;
}

// ---------------- x -> fp16 conversion, pre-scaled by s_out[row] ----------------
__global__ __launch_bounds__(256) void xhalf_kernel(const float* __restrict__ x,
                                                    const float* __restrict__ s_out,
                                                    unsigned short* __restrict__ xh) {
  int base = (blockIdx.x * 256 + threadIdx.x) * 8;
  if (base < N_NODES * IN_DIM) {
    float sc = s_out[base >> 7];  // row = base / IN_DIM
    float4 a = *reinterpret_cast<const float4*>(&x[base]);
    float4 b = *reinterpret_cast<const float4*>(&x[base + 4]);
    unsigned short o[8];
    const float* pa = &a.x;
    const float* pb = &b.x;
#pragma unroll
    for (int q = 0; q < 4; q++) o[q] = f2h(pa[q] * sc);
#pragma unroll
    for (int q = 0; q < 4; q++) o[4 + q] = f2h(pb[q] * sc);
    *reinterpret_cast<uint4*>(&xh[base]) = *reinterpret_cast<const uint4*>(o);
  }
}

// ---- W split+transpose (both weights, one launch) ----
__global__ __launch_bounds__(256) void wsplit_kernel(const float* __restrict__ W1,
                                                     unsigned* __restrict__ Wt1,
                                                     const float* __restrict__ W2,
                                                     unsigned* __restrict__ Wt2) {
  int i = blockIdx.x * 256 + threadIdx.x;
  constexpr int N1 = IN_DIM * 256;
  if (i < N1) {
    int k = i >> 8;
    int n = i & 255;
    Wt1[(size_t)n * IN_DIM + k] = pack_split(W1[i]);
  } else {
    int j = i - N1;
    if (j < HID_DIM * 256) {
      int k = j >> 8;
      int n = j & 255;
      Wt2[(size_t)n * HID_DIM + k] = pack_split(W2[j]);
    }
  }
}

// ---------------- padded-CSR gather (rows pre-scaled by s_out) ----------------
// 4 waves/block = 4 nodes; node idx wave-uniform (s_load path); 8-deep edge unroll.
// MODE: 1 = bf16 rows, 2 = fp16 rows.
template <int D, int MODE>
__global__ __launch_bounds__(256) void gather_kernel(const void* __restrict__ hsrc,
                                                     const float* __restrict__ s_in,
                                                     const int* __restrict__ cntIn,
                                                     const unsigned short* __restrict__ eidx,
                                                     unsigned* __restrict__ aggp) {
  constexpr int VEC = D / 64;  // 4 (D=256) or 2 (D=128)
  const int node = __builtin_amdgcn_readfirstlane(blockIdx.x * 4 + (threadIdx.x >> 6));
  const int lane = threadIdx.x & 63;
  const int f0 = lane * VEC;
  const int beg = node * CAP;
  const int end = beg + cntIn[node];
  float acc[VEC] = {};
  int j = beg;
  for (; j + 7 < end; j += 8) {
    int s[8];
#pragma unroll
    for (int u = 0; u < 8; u++) s[u] = (int)eidx[j + u];
    float v[8][VEC];
#pragma unroll
    for (int u = 0; u < 8; u++) {
      const unsigned short* row = (const unsigned short*)hsrc + (size_t)s[u] * D + f0;
      if constexpr (VEC == 4) {
        uint2 rv = *reinterpret_cast<const uint2*>(row);
        unsigned short w[4] = {(unsigned short)(rv.x & 0xffffu), (unsigned short)(rv.x >> 16),
                               (unsigned short)(rv.y & 0xffffu), (unsigned short)(rv.y >> 16)};
#pragma unroll
        for (int q = 0; q < 4; q++) v[u][q] = (MODE == 1) ? bf2f(w[q]) : h2f(w[q]);
      } else {
        unsigned rv = *reinterpret_cast<const unsigned*>(row);
        unsigned short w[2] = {(unsigned short)(rv & 0xffffu), (unsigned short)(rv >> 16)};
#pragma unroll
        for (int q = 0; q < 2; q++) v[u][q] = (MODE == 1) ? bf2f(w[q]) : h2f(w[q]);
      }
    }
#pragma unroll
    for (int u = 0; u < 8; u++)
#pragma unroll
      for (int q = 0; q < VEC; q++) acc[q] += v[u][q];
  }
  for (; j < end; j++) {
    int s = (int)eidx[j];
    const unsigned short* row = (const unsigned short*)hsrc + (size_t)s * D + f0;
#pragma unroll
    for (int q = 0; q < VEC; q++)
      acc[q] += (MODE == 1) ? bf2f(row[q]) : h2f(row[q]);
  }
  float si = s_in[node];
#pragma unroll
  for (int q = 0; q < VEC; q++) aggp[(size_t)node * D + f0 + q] = pack_split(acc[q] * si);
}

// ---------------- MFMA GEMM: O = lrelu(A @ W + b) [* oscale[row]], split-bf16 3-product ----------------
template <int K, bool OUT_BF16>
__global__ __launch_bounds__(256) void gemm_mfma_bias_lrelu(const unsigned* __restrict__ Apk,
                                                            const unsigned* __restrict__ Wt,
                                                            const float* __restrict__ bias,
                                                            const float* __restrict__ oscale,
                                                            void* __restrict__ Optr, int M) {
  constexpr int BM = 128, BN = 128, BK = 32;
  constexpr int LDK = BK + 8;  // 40 ushorts/row: frag b128 reads 2-way bank alias (free)
  __shared__ unsigned short Ah[BM][LDK], Al[BM][LDK];
  __shared__ unsigned short Bh[BN][LDK], Bl[BN][LDK];
  const int tid = threadIdx.x;
  const int lane = tid & 63;
  const int wave = tid >> 6;
  const int wr = wave >> 1, wc = wave & 1;  // 2x2 wave grid, 64x64 each
  const int rowBase = blockIdx.x * BM;
  const int colBase = blockIdx.y * BN;
  const int g = lane >> 4;    // 0..3  -> k-group / C row-group
  const int r16 = lane & 15;  // fragment row/col

  f32x4 acc[4][4] = {};

  for (int k0 = 0; k0 < K; k0 += BK) {
#pragma unroll
    for (int p = 0; p < 4; p++) {
      int e = (p * 256 + tid) * 4;
      int r = e >> 5;
      int kc = e & 31;
      int gr = rowBase + r;
      if (gr >= M) gr = M - 1;  // clamp; stores guarded
      uint4 v = *reinterpret_cast<const uint4*>(&Apk[(size_t)gr * K + k0 + kc]);
      *reinterpret_cast<unsigned*>(&Ah[r][kc]) = (v.x & 0xffffu) | (v.y << 16);
      *reinterpret_cast<unsigned*>(&Ah[r][kc + 2]) = (v.z & 0xffffu) | (v.w << 16);
      *reinterpret_cast<unsigned*>(&Al[r][kc]) = (v.x >> 16) | (v.y & 0xffff0000u);
      *reinterpret_cast<unsigned*>(&Al[r][kc + 2]) = (v.z >> 16) | (v.w & 0xffff0000u);
    }
#pragma unroll
    for (int p = 0; p < 4; p++) {
      int e = (p * 256 + tid) * 4;
      int n = e >> 5;
      int kc = e & 31;
      uint4 v = *reinterpret_cast<const uint4*>(&Wt[(size_t)(colBase + n) * K + k0 + kc]);
      *reinterpret_cast<unsigned*>(&Bh[n][kc]) = (v.x & 0xffffu) | (v.y << 16);
      *reinterpret_cast<unsigned*>(&Bh[n][kc + 2]) = (v.z & 0xffffu) | (v.w << 16);
      *reinterpret_cast<unsigned*>(&Bl[n][kc]) = (v.x >> 16) | (v.y & 0xffff0000u);
      *reinterpret_cast<unsigned*>(&Bl[n][kc + 2]) = (v.z >> 16) | (v.w & 0xffff0000u);
    }
    __syncthreads();

    bf16x8 afh[4], afl[4], bfh[4], bfl[4];
#pragma unroll
    for (int mf = 0; mf < 4; mf++) {
      afh[mf] = *reinterpret_cast<const bf16x8*>(&Ah[wr * 64 + mf * 16 + r16][g * 8]);
      afl[mf] = *reinterpret_cast<const bf16x8*>(&Al[wr * 64 + mf * 16 + r16][g * 8]);
    }
#pragma unroll
    for (int nf = 0; nf < 4; nf++) {
      bfh[nf] = *reinterpret_cast<const bf16x8*>(&Bh[wc * 64 + nf * 16 + r16][g * 8]);
      bfl[nf] = *reinterpret_cast<const bf16x8*>(&Bl[wc * 64 + nf * 16 + r16][g * 8]);
    }
#pragma unroll
    for (int mf = 0; mf < 4; mf++)
#pragma unroll
      for (int nf = 0; nf < 4; nf++) {
        acc[mf][nf] = __builtin_amdgcn_mfma_f32_16x16x32_bf16(afh[mf], bfh[nf], acc[mf][nf], 0, 0, 0);
        acc[mf][nf] = __builtin_amdgcn_mfma_f32_16x16x32_bf16(afh[mf], bfl[nf], acc[mf][nf], 0, 0, 0);
        acc[mf][nf] = __builtin_amdgcn_mfma_f32_16x16x32_bf16(afl[mf], bfh[nf], acc[mf][nf], 0, 0, 0);
      }
    __syncthreads();
  }

#pragma unroll
  for (int mf = 0; mf < 4; mf++)
#pragma unroll
    for (int nf = 0; nf < 4; nf++) {
      int col = colBase + wc * 64 + nf * 16 + r16;
      float bv = bias[col];
#pragma unroll
      for (int j = 0; j < 4; j++) {
        int row = rowBase + wr * 64 + mf * 16 + g * 4 + j;
        if (row < M) {
          float v = acc[mf][nf][j] + bv;
          v = v > 0.0f ? v : NEG_SLOPE * v;
          if (oscale) v *= oscale[row];
          if constexpr (OUT_BF16) {
            ((unsigned short*)Optr)[(size_t)row * 256 + col] = f2bf(v);
          } else {
            ((float*)Optr)[(size_t)row * 256 + col] = v;
          }
        }
      }
    }
}

// ---------------- per-graph mean pooling (graph_ids sorted) ----------------
__global__ __launch_bounds__(64) void pool_kernel(const float* __restrict__ h,
                                                  const int* __restrict__ gids,
                                                  float* __restrict__ sums,
                                                  float* __restrict__ counts, int nNodes) {
  constexpr int NB = 32;  // nodes per block
  const int lane = threadIdx.x;
  const int n0 = blockIdx.x * NB;
  float4 acc = {0.0f, 0.0f, 0.0f, 0.0f};
  int cur = -1;
  int cnt = 0;
  for (int i = 0; i < NB; i++) {
    int n = n0 + i;
    if (n >= nNodes) break;
    int g = gids[n];
    if (g != cur) {
      if (cur >= 0) {
        float* sp = &sums[(size_t)cur * 256 + lane * 4];
        atomicAdd(sp + 0, acc.x);
        atomicAdd(sp + 1, acc.y);
        atomicAdd(sp + 2, acc.z);
        atomicAdd(sp + 3, acc.w);
        if (lane == 0) atomicAdd(&counts[cur], (float)cnt);
      }
      cur = g;
      acc = {0.0f, 0.0f, 0.0f, 0.0f};
      cnt = 0;
    }
    float4 v = *reinterpret_cast<const float4*>(&h[(size_t)n * 256 + lane * 4]);
    acc.x += v.x;
    acc.y += v.y;
    acc.z += v.z;
    acc.w += v.w;
    cnt++;
  }
  if (cur >= 0) {
    float* sp = &sums[(size_t)cur * 256 + lane * 4];
    atomicAdd(sp + 0, acc.x);
    atomicAdd(sp + 1, acc.y);
    atomicAdd(sp + 2, acc.z);
    atomicAdd(sp + 3, acc.w);
    if (lane == 0) atomicAdd(&counts[cur], (float)cnt);
  }
}

// ---------------- classifier: out = (sums/count) @ Wc + bc ----------------
__global__ __launch_bounds__(256) void cls_kernel(const float* __restrict__ sums,
                                                  const float* __restrict__ counts,
                                                  const float* __restrict__ Wc,
                                                  const float* __restrict__ bc,
                                                  float* __restrict__ out) {
  __shared__ float hg[256];
  int g = blockIdx.x;
  float invc = 1.0f / fmaxf(counts[g], 1.0f);
  hg[threadIdx.x] = sums[(size_t)g * 256 + threadIdx.x] * invc;
  __syncthreads();
  if (threadIdx.x < N_CLASSES) {
    float a = bc[threadIdx.x];
    for (int k = 0; k < 256; k++) a += hg[k] * Wc[k * N_CLASSES + threadIdx.x];
    out[g * N_CLASSES + threadIdx.x] = a;
  }
}

static constexpr size_t align1k(size_t x) { return (x + 1023) & ~(size_t)1023; }

extern "C" void kernel_launch(void* const* d_in, const int* in_sizes, int n_in,
                              void* d_out, int out_size, void* d_ws, size_t ws_size,
                              hipStream_t stream) {
  const float* x = (const float*)d_in[0];
  const int* src = (const int*)d_in[1];
  const int* dst = (const int*)d_in[2];
  const int* gids = (const int*)d_in[3];
  const float* W1 = (const float*)d_in[4];
  const float* b1 = (const float*)d_in[5];
  const float* W2 = (const float*)d_in[6];
  const float* b2 = (const float*)d_in[7];
  const float* Wc = (const float*)d_in[8];
  const float* bc = (const float*)d_in[9];
  float* out = (float*)d_out;

  // ---------------- workspace layout ----------------
  char* ws = (char*)d_ws;
  constexpr size_t OFF_CNT_IN = 0;                                   // 40000 ints
  constexpr size_t OFF_CNT_OUT = OFF_CNT_IN + (size_t)N_NODES * 4;   // 40000 ints (contiguous memset)
  constexpr size_t OFF_SIN = align1k(OFF_CNT_OUT + (size_t)N_NODES * 4);
  constexpr size_t OFF_SOUT = OFF_SIN + (size_t)N_NODES * 4;
  constexpr size_t OFF_PCNT = align1k(OFF_SOUT + (size_t)N_NODES * 4);  // 128 floats
  constexpr size_t OFF_SUMS = align1k(OFF_PCNT + 512);                  // 128*256 floats
  constexpr size_t OFF_EIDX = align1k(OFF_SUMS + (size_t)N_GRAPHS * 256 * 4);  // 40000*64 ushort
  constexpr size_t OFF_AGG = align1k(OFF_EIDX + (size_t)N_NODES * CAP * 2);
  constexpr size_t SZ_BIG = (size_t)N_NODES * 256 * 4;  // 40,960,000
  constexpr size_t OFF_H = align1k(OFF_AGG + SZ_BIG);   // h1 (bf16) then h2 (fp32)
  constexpr size_t OFF_WT1 = align1k(OFF_H + SZ_BIG);
  constexpr size_t OFF_WT2 = align1k(OFF_WT1 + 256 * 128 * 4);
  constexpr size_t OFF_XH = align1k(OFF_WT2 + 256 * 256 * 4);  // fp16 x: 40000*128*2

  int* cntIn = (int*)(ws + OFF_CNT_IN);
  int* cntOut = (int*)(ws + OFF_CNT_OUT);
  float* s_in = (float*)(ws + OFF_SIN);
  float* s_out = (float*)(ws + OFF_SOUT);
  float* counts = (float*)(ws + OFF_PCNT);
  float* sums = (float*)(ws + OFF_SUMS);
  unsigned short* eidx = (unsigned short*)(ws + OFF_EIDX);
  unsigned* aggp = (unsigned*)(ws + OFF_AGG);
  unsigned short* h1b = (unsigned short*)(ws + OFF_H);  // bf16 layer-1 activations (pre-scaled)
  float* h2 = (float*)(ws + OFF_H);                     // fp32 layer-2 activations
  unsigned* Wt1 = (unsigned*)(ws + OFF_WT1);
  unsigned* Wt2 = (unsigned*)(ws + OFF_WT2);
  unsigned short* xh = (unsigned short*)(ws + OFF_XH);

  // floats to zero starting at OFF_PCNT (counts pad + sums) — done inside degscale
  const int nZero = (int)((OFF_SUMS - OFF_PCNT) / 4 + (size_t)N_GRAPHS * 256);

  // ---------------- CSR build (merged hist+fill, padded) + scales + conversions ----------------
  hipMemsetAsync(ws + OFF_CNT_IN, 0, 2 * (size_t)N_NODES * 4, stream);
  wsplit_kernel<<<((IN_DIM + HID_DIM) * 256 + 255) / 256, 256, 0, stream>>>(W1, Wt1, W2, Wt2);
  fill_padded_kernel<<<(N_EDGES + 255) / 256, 256, 0, stream>>>(src, dst, cntIn, cntOut, eidx, N_EDGES);
  degscale_kernel<<<DS_BLOCKS, 256, 0, stream>>>(cntIn, cntOut, s_in, s_out, counts, nZero);
  xhalf_kernel<<<(N_NODES * IN_DIM / 8 + 255) / 256, 256, 0, stream>>>(x, s_out, xh);

  dim3 ggrid((N_NODES + 127) / 128, 2);

  // ---------------- layer 1 (gather pre-scaled fp16 x; h1 stored bf16 pre-scaled by s_out) ----------------
  gather_kernel<IN_DIM, 2><<<N_NODES / 4, 256, 0, stream>>>(xh, s_in, cntIn, eidx, aggp);
  gemm_mfma_bias_lrelu<IN_DIM, true><<<ggrid, 256, 0, stream>>>(aggp, Wt1, b1, s_out, h1b, N_NODES);

  // ---------------- layer 2 (gather pre-scaled bf16 h1; h2 fp32 unscaled) ----------------
  gather_kernel<HID_DIM, 1><<<N_NODES / 4, 256, 0, stream>>>(h1b, s_in, cntIn, eidx, aggp);
  gemm_mfma_bias_lrelu<HID_DIM, false><<<ggrid, 256, 0, stream>>>(aggp, Wt2, b2, nullptr, h2, N_NODES);

  // ---------------- pooling + classifier ----------------
  pool_kernel<<<(N_NODES + 31) / 32, 64, 0, stream>>>(h2, gids, sums, counts, N_NODES);
  cls_kernel<<<N_GRAPHS, 256, 0, stream>>>(sums, counts, Wc, bc, out);
}

// Round 14
// 308.949 us; speedup vs baseline: 1.7849x; 1.0851x over previous
//
#include <hip/hip_runtime.h>

#define N_NODES 40000
#define N_EDGES 640000
#define IN_DIM 128
#define HID_DIM 256
#define OUT_DIM 256
#define N_CLASSES 10
#define N_GRAPHS 128
#define NEG_SLOPE 0.01f
#define CAP 64  // padded-CSR slots per node; in-deg ~ Poisson(16), P(>=64) ~ 3e-22

#define DS_BLOCKS ((N_NODES + 255) / 256)  // 157

typedef short bf16x8 __attribute__((ext_vector_type(8)));
typedef float f32x4 __attribute__((ext_vector_type(4)));

// ---- numeric helpers ----
__device__ inline unsigned short f2bf(float x) {
  unsigned u = __float_as_uint(x);
  u += 0x7fffu + ((u >> 16) & 1u);
  return (unsigned short)(u >> 16);
}
__device__ inline float bf2f(unsigned short h) {
  return __uint_as_float(((unsigned)h) << 16);
}
__device__ inline unsigned pack_split(float v) {
  unsigned short hi = f2bf(v);
  float r = v - bf2f(hi);
  unsigned short lo = f2bf(r);
  return (unsigned)hi | ((unsigned)lo << 16);
}
__device__ inline float h2f(unsigned short u) {
  _Float16 h;
  __builtin_memcpy(&h, &u, 2);
  return (float)h;
}
__device__ inline unsigned short f2h(float x) {
  _Float16 h = (_Float16)x;
  unsigned short u;
  __builtin_memcpy(&u, &h, 2);
  return u;
}
// fp8 e4m3 (OCP on gfx950) via HW cvt
__device__ inline unsigned char f2fp8(float v) {
  int r = __builtin_amdgcn_cvt_pk_fp8_f32(v, v, 0, false);
  return (unsigned char)(r & 0xff);
}

// ---------------- merged hist+fill: padded CSR in one edge pass ----------------
__global__ __launch_bounds__(256) void fill_padded_kernel(const int* __restrict__ src,
                                                          const int* __restrict__ dst,
                                                          int* __restrict__ cntIn,
                                                          int* __restrict__ cntOut,
                                                          unsigned short* __restrict__ eidx,
                                                          int nEdges) {
  int e = blockIdx.x * 256 + threadIdx.x;
  if (e < nEdges) {
    int s = src[e];
    int d = dst[e];
    int pos = atomicAdd(&cntIn[d], 1);
    eidx[(size_t)d * CAP + pos] = (unsigned short)s;
    atomicAdd(&cntOut[s], 1);
  }
}

// ---------------- degree scales + pool-buffer zeroing ----------------
__global__ __launch_bounds__(256) void degscale_kernel(const int* __restrict__ cntIn,
                                                       const int* __restrict__ cntOut,
                                                       float* __restrict__ sIn,
                                                       float* __restrict__ sOut,
                                                       float* __restrict__ poolZero, int nZero) {
  int i = blockIdx.x * 256 + threadIdx.x;
  if (i < N_NODES) {
    sIn[i] = rsqrtf((float)max(cntIn[i], 1));
    sOut[i] = rsqrtf((float)max(cntOut[i], 1));
  }
  if (i < nZero) poolZero[i] = 0.0f;
}

// ---------------- x -> fp16 conversion, pre-scaled by s_out[row] ----------------
__global__ __launch_bounds__(256) void xhalf_kernel(const float* __restrict__ x,
                                                    const float* __restrict__ s_out,
                                                    unsigned short* __restrict__ xh) {
  int base = (blockIdx.x * 256 + threadIdx.x) * 8;
  if (base < N_NODES * IN_DIM) {
    float sc = s_out[base >> 7];  // row = base / IN_DIM
    float4 a = *reinterpret_cast<const float4*>(&x[base]);
    float4 b = *reinterpret_cast<const float4*>(&x[base + 4]);
    unsigned short o[8];
    const float* pa = &a.x;
    const float* pb = &b.x;
#pragma unroll
    for (int q = 0; q < 4; q++) o[q] = f2h(pa[q] * sc);
#pragma unroll
    for (int q = 0; q < 4; q++) o[4 + q] = f2h(pb[q] * sc);
    *reinterpret_cast<uint4*>(&xh[base]) = *reinterpret_cast<const uint4*>(o);
  }
}

// ---- W split+transpose (both weights, one launch) ----
__global__ __launch_bounds__(256) void wsplit_kernel(const float* __restrict__ W1,
                                                     unsigned* __restrict__ Wt1,
                                                     const float* __restrict__ W2,
                                                     unsigned* __restrict__ Wt2) {
  int i = blockIdx.x * 256 + threadIdx.x;
  constexpr int N1 = IN_DIM * 256;
  if (i < N1) {
    int k = i >> 8;
    int n = i & 255;
    Wt1[(size_t)n * IN_DIM + k] = pack_split(W1[i]);
  } else {
    int j = i - N1;
    if (j < HID_DIM * 256) {
      int k = j >> 8;
      int n = j & 255;
      Wt2[(size_t)n * HID_DIM + k] = pack_split(W2[j]);
    }
  }
}

// ---------------- padded-CSR gather (rows pre-scaled by s_out) ----------------
// 4 waves/block = 4 nodes; node idx wave-uniform (s_load path); 8-deep edge unroll.
// MODE: 2 = fp16 rows, 3 = fp8 e4m3 rows (VEC==4 only).
template <int D, int MODE>
__global__ __launch_bounds__(256) void gather_kernel(const void* __restrict__ hsrc,
                                                     const float* __restrict__ s_in,
                                                     const int* __restrict__ cntIn,
                                                     const unsigned short* __restrict__ eidx,
                                                     unsigned* __restrict__ aggp) {
  constexpr int VEC = D / 64;  // 4 (D=256) or 2 (D=128)
  const int node = __builtin_amdgcn_readfirstlane(blockIdx.x * 4 + (threadIdx.x >> 6));
  const int lane = threadIdx.x & 63;
  const int f0 = lane * VEC;
  const int beg = node * CAP;
  const int end = beg + cntIn[node];
  float acc[VEC] = {};
  int j = beg;
  for (; j + 7 < end; j += 8) {
    int s[8];
#pragma unroll
    for (int u = 0; u < 8; u++) s[u] = (int)eidx[j + u];
    float v[8][VEC];
#pragma unroll
    for (int u = 0; u < 8; u++) {
      if constexpr (MODE == 3) {
        unsigned rv = *reinterpret_cast<const unsigned*>((const unsigned char*)hsrc +
                                                         (size_t)s[u] * D + f0);
        v[u][0] = __builtin_amdgcn_cvt_f32_fp8((int)rv, 0);
        v[u][1] = __builtin_amdgcn_cvt_f32_fp8((int)rv, 1);
        v[u][2] = __builtin_amdgcn_cvt_f32_fp8((int)rv, 2);
        v[u][3] = __builtin_amdgcn_cvt_f32_fp8((int)rv, 3);
      } else {
        const unsigned short* row = (const unsigned short*)hsrc + (size_t)s[u] * D + f0;
        if constexpr (VEC == 4) {
          uint2 rv = *reinterpret_cast<const uint2*>(row);
          unsigned short w[4] = {(unsigned short)(rv.x & 0xffffu), (unsigned short)(rv.x >> 16),
                                 (unsigned short)(rv.y & 0xffffu), (unsigned short)(rv.y >> 16)};
#pragma unroll
          for (int q = 0; q < 4; q++) v[u][q] = h2f(w[q]);
        } else {
          unsigned rv = *reinterpret_cast<const unsigned*>(row);
          v[u][0] = h2f((unsigned short)(rv & 0xffffu));
          v[u][1] = h2f((unsigned short)(rv >> 16));
        }
      }
    }
#pragma unroll
    for (int u = 0; u < 8; u++)
#pragma unroll
      for (int q = 0; q < VEC; q++) acc[q] += v[u][q];
  }
  for (; j < end; j++) {
    int s = (int)eidx[j];
    if constexpr (MODE == 3) {
      unsigned rv = *reinterpret_cast<const unsigned*>((const unsigned char*)hsrc +
                                                       (size_t)s * D + f0);
      acc[0] += __builtin_amdgcn_cvt_f32_fp8((int)rv, 0);
      acc[1] += __builtin_amdgcn_cvt_f32_fp8((int)rv, 1);
      acc[2] += __builtin_amdgcn_cvt_f32_fp8((int)rv, 2);
      acc[3] += __builtin_amdgcn_cvt_f32_fp8((int)rv, 3);
    } else {
      const unsigned short* row = (const unsigned short*)hsrc + (size_t)s * D + f0;
#pragma unroll
      for (int q = 0; q < VEC; q++) acc[q] += h2f(row[q]);
    }
  }
  float si = s_in[node];
#pragma unroll
  for (int q = 0; q < VEC; q++) aggp[(size_t)node * D + f0 + q] = pack_split(acc[q] * si);
}

// ---------------- MFMA GEMM: O = lrelu(A @ W + b) [* oscale[row]], split-bf16 3-product ----------------
// OMODE: 0 = fp32 out, 2 = fp8 e4m3 out (scaled)
template <int K, int OMODE>
__global__ __launch_bounds__(256) void gemm_mfma_bias_lrelu(const unsigned* __restrict__ Apk,
                                                            const unsigned* __restrict__ Wt,
                                                            const float* __restrict__ bias,
                                                            const float* __restrict__ oscale,
                                                            void* __restrict__ Optr, int M) {
  constexpr int BM = 128, BN = 128, BK = 32;
  constexpr int LDK = BK + 8;  // 40 ushorts/row: frag b128 reads 2-way bank alias (free)
  __shared__ unsigned short Ah[BM][LDK], Al[BM][LDK];
  __shared__ unsigned short Bh[BN][LDK], Bl[BN][LDK];
  const int tid = threadIdx.x;
  const int lane = tid & 63;
  const int wave = tid >> 6;
  const int wr = wave >> 1, wc = wave & 1;  // 2x2 wave grid, 64x64 each
  const int rowBase = blockIdx.x * BM;
  const int colBase = blockIdx.y * BN;
  const int g = lane >> 4;    // 0..3  -> k-group / C row-group
  const int r16 = lane & 15;  // fragment row/col

  f32x4 acc[4][4] = {};

  for (int k0 = 0; k0 < K; k0 += BK) {
#pragma unroll
    for (int p = 0; p < 4; p++) {
      int e = (p * 256 + tid) * 4;
      int r = e >> 5;
      int kc = e & 31;
      int gr = rowBase + r;
      if (gr >= M) gr = M - 1;  // clamp; stores guarded
      uint4 v = *reinterpret_cast<const uint4*>(&Apk[(size_t)gr * K + k0 + kc]);
      *reinterpret_cast<unsigned*>(&Ah[r][kc]) = (v.x & 0xffffu) | (v.y << 16);
      *reinterpret_cast<unsigned*>(&Ah[r][kc + 2]) = (v.z & 0xffffu) | (v.w << 16);
      *reinterpret_cast<unsigned*>(&Al[r][kc]) = (v.x >> 16) | (v.y & 0xffff0000u);
      *reinterpret_cast<unsigned*>(&Al[r][kc + 2]) = (v.z >> 16) | (v.w & 0xffff0000u);
    }
#pragma unroll
    for (int p = 0; p < 4; p++) {
      int e = (p * 256 + tid) * 4;
      int n = e >> 5;
      int kc = e & 31;
      uint4 v = *reinterpret_cast<const uint4*>(&Wt[(size_t)(colBase + n) * K + k0 + kc]);
      *reinterpret_cast<unsigned*>(&Bh[n][kc]) = (v.x & 0xffffu) | (v.y << 16);
      *reinterpret_cast<unsigned*>(&Bh[n][kc + 2]) = (v.z & 0xffffu) | (v.w << 16);
      *reinterpret_cast<unsigned*>(&Bl[n][kc]) = (v.x >> 16) | (v.y & 0xffff0000u);
      *reinterpret_cast<unsigned*>(&Bl[n][kc + 2]) = (v.z >> 16) | (v.w & 0xffff0000u);
    }
    __syncthreads();

    bf16x8 afh[4], afl[4], bfh[4], bfl[4];
#pragma unroll
    for (int mf = 0; mf < 4; mf++) {
      afh[mf] = *reinterpret_cast<const bf16x8*>(&Ah[wr * 64 + mf * 16 + r16][g * 8]);
      afl[mf] = *reinterpret_cast<const bf16x8*>(&Al[wr * 64 + mf * 16 + r16][g * 8]);
    }
#pragma unroll
    for (int nf = 0; nf < 4; nf++) {
      bfh[nf] = *reinterpret_cast<const bf16x8*>(&Bh[wc * 64 + nf * 16 + r16][g * 8]);
      bfl[nf] = *reinterpret_cast<const bf16x8*>(&Bl[wc * 64 + nf * 16 + r16][g * 8]);
    }
#pragma unroll
    for (int mf = 0; mf < 4; mf++)
#pragma unroll
      for (int nf = 0; nf < 4; nf++) {
        acc[mf][nf] = __builtin_amdgcn_mfma_f32_16x16x32_bf16(afh[mf], bfh[nf], acc[mf][nf], 0, 0, 0);
        acc[mf][nf] = __builtin_amdgcn_mfma_f32_16x16x32_bf16(afh[mf], bfl[nf], acc[mf][nf], 0, 0, 0);
        acc[mf][nf] = __builtin_amdgcn_mfma_f32_16x16x32_bf16(afl[mf], bfh[nf], acc[mf][nf], 0, 0, 0);
      }
    __syncthreads();
  }

#pragma unroll
  for (int mf = 0; mf < 4; mf++)
#pragma unroll
    for (int nf = 0; nf < 4; nf++) {
      int col = colBase + wc * 64 + nf * 16 + r16;
      float bv = bias[col];
#pragma unroll
      for (int j = 0; j < 4; j++) {
        int row = rowBase + wr * 64 + mf * 16 + g * 4 + j;
        if (row < M) {
          float v = acc[mf][nf][j] + bv;
          v = v > 0.0f ? v : NEG_SLOPE * v;
          if constexpr (OMODE == 2) {
            v *= oscale[row];
            ((unsigned char*)Optr)[(size_t)row * 256 + col] = f2fp8(v);
          } else {
            ((float*)Optr)[(size_t)row * 256 + col] = v;
          }
        }
      }
    }
}

// ---------------- per-graph mean pooling (graph_ids sorted) ----------------
__global__ __launch_bounds__(64) void pool_kernel(const float* __restrict__ h,
                                                  const int* __restrict__ gids,
                                                  float* __restrict__ sums,
                                                  float* __restrict__ counts, int nNodes) {
  constexpr int NB = 32;  // nodes per block
  const int lane = threadIdx.x;
  const int n0 = blockIdx.x * NB;
  float4 acc = {0.0f, 0.0f, 0.0f, 0.0f};
  int cur = -1;
  int cnt = 0;
  for (int i = 0; i < NB; i++) {
    int n = n0 + i;
    if (n >= nNodes) break;
    int g = gids[n];
    if (g != cur) {
      if (cur >= 0) {
        float* sp = &sums[(size_t)cur * 256 + lane * 4];
        atomicAdd(sp + 0, acc.x);
        atomicAdd(sp + 1, acc.y);
        atomicAdd(sp + 2, acc.z);
        atomicAdd(sp + 3, acc.w);
        if (lane == 0) atomicAdd(&counts[cur], (float)cnt);
      }
      cur = g;
      acc = {0.0f, 0.0f, 0.0f, 0.0f};
      cnt = 0;
    }
    float4 v = *reinterpret_cast<const float4*>(&h[(size_t)n * 256 + lane * 4]);
    acc.x += v.x;
    acc.y += v.y;
    acc.z += v.z;
    acc.w += v.w;
    cnt++;
  }
  if (cur >= 0) {
    float* sp = &sums[(size_t)cur * 256 + lane * 4];
    atomicAdd(sp + 0, acc.x);
    atomicAdd(sp + 1, acc.y);
    atomicAdd(sp + 2, acc.z);
    atomicAdd(sp + 3, acc.w);
    if (lane == 0) atomicAdd(&counts[cur], (float)cnt);
  }
}

// ---------------- classifier: out = (sums/count) @ Wc + bc ----------------
__global__ __launch_bounds__(256) void cls_kernel(const float* __restrict__ sums,
                                                  const float* __restrict__ counts,
                                                  const float* __restrict__ Wc,
                                                  const float* __restrict__ bc,
                                                  float* __restrict__ out) {
  __shared__ float hg[256];
  int g = blockIdx.x;
  float invc = 1.0f / fmaxf(counts[g], 1.0f);
  hg[threadIdx.x] = sums[(size_t)g * 256 + threadIdx.x] * invc;
  __syncthreads();
  if (threadIdx.x < N_CLASSES) {
    float a = bc[threadIdx.x];
    for (int k = 0; k < 256; k++) a += hg[k] * Wc[k * N_CLASSES + threadIdx.x];
    out[g * N_CLASSES + threadIdx.x] = a;
  }
}

static constexpr size_t align1k(size_t x) { return (x + 1023) & ~(size_t)1023; }

extern "C" void kernel_launch(void* const* d_in, const int* in_sizes, int n_in,
                              void* d_out, int out_size, void* d_ws, size_t ws_size,
                              hipStream_t stream) {
  const float* x = (const float*)d_in[0];
  const int* src = (const int*)d_in[1];
  const int* dst = (const int*)d_in[2];
  const int* gids = (const int*)d_in[3];
  const float* W1 = (const float*)d_in[4];
  const float* b1 = (const float*)d_in[5];
  const float* W2 = (const float*)d_in[6];
  const float* b2 = (const float*)d_in[7];
  const float* Wc = (const float*)d_in[8];
  const float* bc = (const float*)d_in[9];
  float* out = (float*)d_out;

  // ---------------- workspace layout ----------------
  char* ws = (char*)d_ws;
  constexpr size_t OFF_CNT_IN = 0;                                   // 40000 ints
  constexpr size_t OFF_CNT_OUT = OFF_CNT_IN + (size_t)N_NODES * 4;   // 40000 ints (contiguous memset)
  constexpr size_t OFF_SIN = align1k(OFF_CNT_OUT + (size_t)N_NODES * 4);
  constexpr size_t OFF_SOUT = OFF_SIN + (size_t)N_NODES * 4;
  constexpr size_t OFF_PCNT = align1k(OFF_SOUT + (size_t)N_NODES * 4);  // 128 floats
  constexpr size_t OFF_SUMS = align1k(OFF_PCNT + 512);                  // 128*256 floats
  constexpr size_t OFF_EIDX = align1k(OFF_SUMS + (size_t)N_GRAPHS * 256 * 4);  // 40000*64 ushort
  constexpr size_t OFF_AGG = align1k(OFF_EIDX + (size_t)N_NODES * CAP * 2);
  constexpr size_t SZ_BIG = (size_t)N_NODES * 256 * 4;  // 40,960,000
  constexpr size_t OFF_H = align1k(OFF_AGG + SZ_BIG);   // h1 (fp8, 10MB) then h2 (fp32, 40MB)
  constexpr size_t OFF_WT1 = align1k(OFF_H + SZ_BIG);
  constexpr size_t OFF_WT2 = align1k(OFF_WT1 + 256 * 128 * 4);
  constexpr size_t OFF_XH = align1k(OFF_WT2 + 256 * 256 * 4);  // fp16 x: 40000*128*2

  int* cntIn = (int*)(ws + OFF_CNT_IN);
  int* cntOut = (int*)(ws + OFF_CNT_OUT);
  float* s_in = (float*)(ws + OFF_SIN);
  float* s_out = (float*)(ws + OFF_SOUT);
  float* counts = (float*)(ws + OFF_PCNT);
  float* sums = (float*)(ws + OFF_SUMS);
  unsigned short* eidx = (unsigned short*)(ws + OFF_EIDX);
  unsigned* aggp = (unsigned*)(ws + OFF_AGG);
  unsigned char* h1f8 = (unsigned char*)(ws + OFF_H);  // fp8 layer-1 activations (pre-scaled)
  float* h2 = (float*)(ws + OFF_H);                    // fp32 layer-2 activations (overwrites h1)
  unsigned* Wt1 = (unsigned*)(ws + OFF_WT1);
  unsigned* Wt2 = (unsigned*)(ws + OFF_WT2);
  unsigned short* xh = (unsigned short*)(ws + OFF_XH);

  // floats to zero starting at OFF_PCNT (counts pad + sums) — done inside degscale
  const int nZero = (int)((OFF_SUMS - OFF_PCNT) / 4 + (size_t)N_GRAPHS * 256);

  // ---------------- CSR build (merged hist+fill, padded) + scales + conversions ----------------
  hipMemsetAsync(ws + OFF_CNT_IN, 0, 2 * (size_t)N_NODES * 4, stream);
  wsplit_kernel<<<((IN_DIM + HID_DIM) * 256 + 255) / 256, 256, 0, stream>>>(W1, Wt1, W2, Wt2);
  fill_padded_kernel<<<(N_EDGES + 255) / 256, 256, 0, stream>>>(src, dst, cntIn, cntOut, eidx, N_EDGES);
  degscale_kernel<<<DS_BLOCKS, 256, 0, stream>>>(cntIn, cntOut, s_in, s_out, counts, nZero);
  xhalf_kernel<<<(N_NODES * IN_DIM / 8 + 255) / 256, 256, 0, stream>>>(x, s_out, xh);

  dim3 ggrid((N_NODES + 127) / 128, 2);

  // ---------------- layer 1 (gather pre-scaled fp16 x; h1 stored fp8 pre-scaled by s_out) ----------------
  gather_kernel<IN_DIM, 2><<<N_NODES / 4, 256, 0, stream>>>(xh, s_in, cntIn, eidx, aggp);
  gemm_mfma_bias_lrelu<IN_DIM, 2><<<ggrid, 256, 0, stream>>>(aggp, Wt1, b1, s_out, h1f8, N_NODES);

  // ---------------- layer 2 (gather fp8 h1; h2 fp32) ----------------
  gather_kernel<HID_DIM, 3><<<N_NODES / 4, 256, 0, stream>>>(h1f8, s_in, cntIn, eidx, aggp);
  gemm_mfma_bias_lrelu<HID_DIM, 0><<<ggrid, 256, 0, stream>>>(aggp, Wt2, b2, nullptr, h2, N_NODES);

  // ---------------- pooling + classifier ----------------
  pool_kernel<<<(N_NODES + 31) / 32, 64, 0, stream>>>(h2, gids, sums, counts, N_NODES);
  cls_kernel<<<N_GRAPHS, 256, 0, stream>>>(sums, counts, Wc, bc, out);
}